// Round 1
// baseline (329.472 us; speedup 1.0000x reference)
//
#include <hip/hip_runtime.h>
#include <hip/hip_bf16.h>

// 2-layer GCN encoder: (GCNConv -> BatchNorm1d(train) -> PReLU) x 2
// N=50000, E=800000, D=128. Inputs f32 (probed), edge_index int64 (probed),
// output f32. Internal: GEMM/agg buffers bf16, math f32.
//
// R14 (this round): chunked L2-resident aggregation.
//  hbuf/aggbuf move to pair-slot CHUNKED layout: chunk c in [0,4) holds u32
//  slot s (s>>4 == c) of every node contiguously: addr = c*NN*16 + node*16 +
//  (s&15). Slot s = bf16 pair (col s, col s+64). Each chunk = 3.2 MB < 4 MB
//  per-XCD L2. k_agg = 4*12500 blocks chunk-major: one 16-lane group per
//  edge (4 edges per wave-iteration, 16-edge unroll = 4 gathers in flight),
//  cross-group shfl_xor reduce, stats via LDS + 64 atomics/block.
//  Gather traffic (205 MB/layer) now served from a per-XCD-resident chunk
//  instead of random LLC. gemm XMODE2 A-path and k_bn_apply read pair-slots.
//
// ws layout (bytes):
//   [0       .. +200000)   dinv f32[NN]
//   [200704  .. +8)        flags: [0]=int64?, [1]=bf16-floats?
//   [404800  .. +200000)   rowptr int[NN] (row starts, gapped CSR)
//   [604816  .. +200000)   rowend int[NN]
//   [805632  .. +256)      tailc int[64] (zeroed by memset; bucket fill counts)
//   [806400  .. +65536)    stats1p f32[64][256]
//   [871936  .. +65536)    stats2p f32[64][256]
//   [1048576 .. +3.7MB)    csr_src int[49*CAP]
//   [4718592 .. +12.8MB)   hbuf  u32[4][NN][16] chunked pair-slots (dinv-scaled)
//   [17518592.. +32768)    wp1 bf16[128*128] swizzled
//   [17551360.. +32768)    wp2 bf16[128*128] swizzled
//   [30056448.. +12.8MB)   aggbuf u32[4][NN][16] chunked pair-slots
//   [42856448.. +3.7MB)    binned uint[49*CAP] packed

typedef __hip_bfloat16 bf16;
typedef __attribute__((ext_vector_type(8))) short short8;   // 8 bf16 = 4 VGPR
typedef __attribute__((ext_vector_type(4))) float f32x4;    // MFMA accumulator

#define NN 50000
#define NE 800000
#define DD 128
#define BN_EPS 1e-5f
#define BIN_CHUNK 3125   // NE / 256 exactly
#define CAP 18432        // per-bucket slot capacity (72*256; mu+16sigma)
#define NBKT 49          // ceil(50000 / 1024)
#define CHS (NN * 16)    // u32 stride of one column-chunk
#define NBAGG 12500      // node-blocks per chunk phase (4 nodes/block)

__device__ __forceinline__ float b2f(bf16 v) { return __bfloat162float(v); }
__device__ __forceinline__ float ldf(const void* p, size_t idx, int isbf) {
  return isbf ? b2f(((const bf16*)p)[idx]) : ((const float*)p)[idx];
}
__device__ __forceinline__ int lde(const void* ei, size_t idx, int is64) {
  return is64 ? (int)((const long long*)ei)[idx] : ((const int*)ei)[idx];
}
__device__ __forceinline__ unsigned int f2bs(float v) {
  bf16 b = __float2bfloat16(v);
  return (unsigned int)*reinterpret_cast<unsigned short*>(&b);
}
__device__ __forceinline__ float bslo(unsigned int u) { return __uint_as_float(u << 16); }
__device__ __forceinline__ float bshi(unsigned int u) { return __uint_as_float(u & 0xFFFF0000u); }
__device__ __forceinline__ float s2f(short v) {
  return __uint_as_float(((unsigned int)(unsigned short)v) << 16);
}

// 256 blocks x 256. Per-block dtype self-probe; block 0 publishes flags;
// blocks 0..63 swizzle W1, 64..127 swizzle W2; all bin their edge chunk into
// packed binned[] at zero-based bucket counters (tailc pre-zeroed).
__global__ __launch_bounds__(256) void k_bin(const int* ei_i, const unsigned short* x16,
                                             const void* W1, const void* W2,
                                             unsigned short* wp1, unsigned short* wp2,
                                             int* flags, int* tailc, unsigned int* binned) {
  __shared__ int cnt[64], cur[64], gb[64], sflags[2];
  __shared__ unsigned int ebuf[BIN_CHUNK];  // 12.5 KB
  const int tid = threadIdx.x;
  const int bid = blockIdx.x;
  if (tid < 64) {
    unsigned long long m1 = __ballot(ei_i[2 * tid + 1] != 0);
    int ex = (x16[2 * tid] >> 7) & 0xFF;
    unsigned long long m2 = __ballot(ex >= 90 && ex <= 140);
    if (tid == 0) {
      sflags[0] = (m1 == 0ull) ? 1 : 0;
      sflags[1] = (__popcll(m2) >= 48) ? 1 : 0;
    }
    cnt[tid] = 0;
    cur[tid] = 0;
  }
  __syncthreads();
  const int is64 = sflags[0], isbf = sflags[1];
  if (bid == 0 && tid == 0) { flags[0] = is64; flags[1] = isbf; }
  if (bid < 128) {  // W swizzle side-job
    const void* W = bid < 64 ? W1 : W2;
    unsigned short* wp = bid < 64 ? wp1 : wp2;
    int idx = (bid & 63) * 256 + tid;
    int k = idx >> 7, n = idx & 127;
    wp[(k >> 3) * 1024 + n * 8 + (k & 7)] = (unsigned short)f2bs(ldf(W, idx, isbf));
  }
  const void* ei = (const void*)ei_i;
  const int e0 = bid * BIN_CHUNK;
  for (int t = tid; t < BIN_CHUNK; t += 256) {
    int s = lde(ei, (size_t)(e0 + t), is64);
    int d = lde(ei, (size_t)NE + e0 + t, is64);
    ebuf[t] = ((unsigned)s << 16) | ((unsigned)(d >> 10) << 10) | (unsigned)(d & 1023);
    atomicAdd(&cnt[d >> 10], 1);
  }
  __syncthreads();
  if (tid < 64 && cnt[tid] > 0) gb[tid] = tid * CAP + atomicAdd(&tailc[tid], cnt[tid]);
  __syncthreads();
  for (int t = tid; t < BIN_CHUNK; t += 256) {
    unsigned int u = ebuf[t];
    int b = (int)((u >> 10) & 63);
    int r = atomicAdd(&cur[b], 1);
    binned[gb[b] + r] = u;
  }
}

// Per-bucket: degree hist (LDS) -> dinv/rowptr/rowend, then exact CSR fill
// with LDS cursors. 49 blocks x 1024. packed u: s=u>>16, dlow=u&1023.
__global__ __launch_bounds__(1024) void k_degfill(const unsigned int* binned, const int* tailc,
                                                  float* dinv, int* rowptr, int* rowend,
                                                  int* csr_src) {
  __shared__ int hist[1024];
  const int b = blockIdx.x;
  const int t = threadIdx.x;
  hist[t] = 0;
  __syncthreads();
  const int eb = b * CAP, ee = eb + tailc[b];
  for (int e = eb + t; e < ee; e += 1024) atomicAdd(&hist[binned[e] & 1023], 1);
  __syncthreads();
  int h = hist[t];
  __syncthreads();
  for (int off = 1; off < 1024; off <<= 1) {  // inclusive scan
    int u = (t >= off) ? hist[t - off] : 0;
    __syncthreads();
    hist[t] += u;
    __syncthreads();
  }
  int start = eb + hist[t] - h;  // exclusive prefix, global position
  int node = b * 1024 + t;
  if (node < NN) {
    rowptr[node] = start;
    rowend[node] = start + h;
    dinv[node] = rsqrtf((float)(h + 1));  // +1 self-loop
  }
  __syncthreads();
  hist[t] = start;  // repurpose as fill cursor
  __syncthreads();
  for (int e = eb + t; e < ee; e += 1024) {
    unsigned int u = binned[e];
    int pos = atomicAdd(&hist[u & 1023], 1);
    csr_src[pos] = (int)(u >> 16);
  }
}

// MFMA GEMM. out = dinv-prescaled bf16 pair-slots in CHUNKED layout: slot
// s of row r at chunk(s>>4)*CHS + r*16 + (s&15). W pre-swizzled (wp).
// XMODE 0: layer-1 input (probe f32/bf16). XMODE 2: aggbuf chunked pair-slots
// + fused BN1 (stats from 64-copy partials statsp). Blocks 0..63 zero zstats
// (consumed by the NEXT kernel's atomics -- stream-ordered, safe).
template <int XMODE>
__global__ __launch_bounds__(256) void k_gemm(const void* in_, const unsigned short* wp,
                                              const int* flags, const float* dinv,
                                              const float* statsp, const void* g,
                                              const void* be, const void* al,
                                              float* zstats, unsigned int* out) {
  __shared__ alignas(16) short sW[16 * 128 * 8];  // 32 KB
  __shared__ float sSc[DD], sSh[DD], sAl;
  const int isbf = flags[1];
  const int tid = threadIdx.x;

  if (blockIdx.x < 64) zstats[blockIdx.x * 256 + tid] = 0.f;
  {
    const short8* src = (const short8*)wp;
    short8* dst = (short8*)sW;
#pragma unroll
    for (int i = 0; i < 8; i++) dst[tid + i * 256] = src[tid + i * 256];
  }
  if (XMODE == 2) {
    if (tid < DD) {
      float s = 0.f, q = 0.f;
#pragma unroll 8
      for (int k = 0; k < 64; k++) {
        s += statsp[k * 256 + tid];
        q += statsp[k * 256 + 128 + tid];
      }
      const float inv_n = 1.0f / NN;
      float mu = s * inv_n;
      float var = q * inv_n - mu * mu;
      float sc = rsqrtf(var + BN_EPS) * ldf(g, tid, isbf);
      sSc[tid] = sc;
      sSh[tid] = ldf(be, tid, isbf) - mu * sc;
    }
    if (tid == 0) sAl = ldf(al, 0, isbf);
  }
  __syncthreads();

  const int wave = tid >> 6;
  const int lane = tid & 63;
  const int quad = lane >> 4;
  const int m16 = lane & 15;
  const int r0 = blockIdx.x * 128 + wave * 32;

  f32x4 acc[2][8];
#pragma unroll
  for (int t = 0; t < 2; t++)
#pragma unroll
    for (int n = 0; n < 8; n++) acc[t][n] = (f32x4){0.f, 0.f, 0.f, 0.f};

#pragma unroll
  for (int q = 0; q < 4; q++) {
    const int kq = q * 32 + quad * 8;
    short8 af[2];
#pragma unroll
    for (int t = 0; t < 2; t++) {
      int row = r0 + t * 16 + m16;
      row = row < NN ? row : NN - 1;  // clamp; garbage rows never stored
      if (XMODE == 2) {
        // pair-slot chunked read: cols kq..kq+7 live in slots (kq&63)..+7,
        // lo half if kq<64 else hi half.
        const int s8 = kq & 63;
        const unsigned int* pr = (const unsigned int*)in_ +
            (size_t)(s8 >> 4) * CHS + (size_t)row * 16 + (s8 & 15);
        const uint4 ra = *(const uint4*)pr;
        const uint4 rb = *(const uint4*)(pr + 4);
        unsigned int uu[8] = {ra.x, ra.y, ra.z, ra.w, rb.x, rb.y, rb.z, rb.w};
        const bool hi = kq >= 64;
        short8 f;
#pragma unroll
        for (int jj = 0; jj < 8; jj++) {
          float y = hi ? bshi(uu[jj]) : bslo(uu[jj]);
          y = y * sSc[kq + jj] + sSh[kq + jj];
          y = y > 0.f ? y : sAl * y;
          f[jj] = (short)f2bs(y);
        }
        af[t] = f;
      } else if (isbf) {
        af[t] = *(const short8*)((const short*)in_ + (size_t)row * DD + kq);
      } else {
        const float* ap = (const float*)in_ + (size_t)row * DD + kq;
        const float4 u0 = *(const float4*)ap;
        const float4 u1 = *(const float4*)(ap + 4);
        float v[8] = {u0.x, u0.y, u0.z, u0.w, u1.x, u1.y, u1.z, u1.w};
        short8 f;
#pragma unroll
        for (int jj = 0; jj < 8; jj++) f[jj] = (short)f2bs(v[jj]);
        af[t] = f;
      }
    }
    const int c = q * 4 + quad;
    const short* bp = sW + c * 1024 + m16 * 8;
#pragma unroll
    for (int n = 0; n < 8; n++) {
      const short8 bfrag = *(const short8*)(bp + n * 128);
      acc[0][n] = __builtin_amdgcn_mfma_f32_16x16x32_bf16(af[0], bfrag, acc[0][n], 0, 0, 0);
      acc[1][n] = __builtin_amdgcn_mfma_f32_16x16x32_bf16(af[1], bfrag, acc[1][n], 0, 0, 0);
    }
  }

#pragma unroll
  for (int t = 0; t < 2; t++)
#pragma unroll
    for (int r = 0; r < 4; r++) {
      int row = r0 + t * 16 + quad * 4 + r;
      if (row < NN) {
        float di = dinv[row];
#pragma unroll
        for (int n = 0; n < 4; n++) {
          // slot s = n*16 + m16 -> chunk n, intra idx m16
          unsigned int p = (f2bs(di * acc[t][n + 4][r]) << 16) | f2bs(di * acc[t][n][r]);
          out[(size_t)n * CHS + (size_t)row * 16 + m16] = p;
        }
      }
    }
}

// Chunked aggregation: grid = 4 chunks x 12500 blocks (chunk-major so each
// phase's 3.2 MB chunk is per-XCD L2-resident). Block = 4 waves = 4
// consecutive nodes, all on chunk c. Within a wave: 16-lane group per edge
// (4 edges per gather instruction), lane handles slot j = lane&15.
// 16-edge unroll = 4 independent gathers in flight. Cross-group shfl_xor
// reduce; output pair-slot chunked; BN stats via LDS + 64 atomics/block.
__global__ __launch_bounds__(256) void k_agg(const unsigned int* hs, const float* dinv,
                                             const int* rowptr, const int* rowend,
                                             const int* csr_src, const void* bias,
                                             const int* flags, unsigned int* out,
                                             float* statsp) {
  const int tid = threadIdx.x;
  const int c = blockIdx.x / NBAGG;        // chunk 0..3 (phase)
  const int nb = blockIdx.x - c * NBAGG;
  const int wave = tid >> 6;
  const int lane = tid & 63;
  const int grp = lane >> 4;               // edge sub-group 0..3
  const int j = lane & 15;                 // slot within chunk
  const int w = nb * 4 + wave;             // node; 12500*4 == NN exactly
  const unsigned int* hc = hs + (size_t)c * CHS;
  const float dd_ = dinv[w];
  unsigned int own = hc[(size_t)w * 16 + j];
  float ax = 0.f, ay = 0.f;
  if (grp == 0) { ax = bslo(own); ay = bshi(own); }  // self-loop once
  int e = rowptr[w];
  const int e1 = rowend[w];
  for (; e + 16 <= e1; e += 16) {
    int s0 = csr_src[e + grp];
    int s1 = csr_src[e + 4 + grp];
    int s2 = csr_src[e + 8 + grp];
    int s3 = csr_src[e + 12 + grp];
    unsigned int v0 = hc[(size_t)s0 * 16 + j];
    unsigned int v1 = hc[(size_t)s1 * 16 + j];
    unsigned int v2 = hc[(size_t)s2 * 16 + j];
    unsigned int v3 = hc[(size_t)s3 * 16 + j];
    ax += bslo(v0) + bslo(v1) + bslo(v2) + bslo(v3);
    ay += bshi(v0) + bshi(v1) + bshi(v2) + bshi(v3);
  }
  for (; e + 8 <= e1; e += 8) {
    int s0 = csr_src[e + grp];
    int s1 = csr_src[e + 4 + grp];
    unsigned int v0 = hc[(size_t)s0 * 16 + j];
    unsigned int v1 = hc[(size_t)s1 * 16 + j];
    ax += bslo(v0) + bslo(v1);
    ay += bshi(v0) + bshi(v1);
  }
  if (e + 4 <= e1) {
    int s0 = csr_src[e + grp];
    unsigned int v0 = hc[(size_t)s0 * 16 + j];
    ax += bslo(v0);
    ay += bshi(v0);
    e += 4;
  }
  if (grp < e1 - e) {  // tail 0..3 edges
    unsigned int v0 = hc[(size_t)csr_src[e + grp] * 16 + j];
    ax += bslo(v0);
    ay += bshi(v0);
  }
  ax += __shfl_xor(ax, 16);
  ax += __shfl_xor(ax, 32);
  ay += __shfl_xor(ay, 16);
  ay += __shfl_xor(ay, 32);
  const int isbf = flags[1];
  const int col1 = c * 16 + j;             // real column (lo); hi = col1+64
  const float o1 = dd_ * ax + ldf(bias, col1, isbf);
  const float o2 = dd_ * ay + ldf(bias, col1 + 64, isbf);
  __shared__ float red[4][4][16];          // [stat][wave][j]
  if (grp == 0) {
    out[(size_t)c * CHS + (size_t)w * 16 + j] = (f2bs(o2) << 16) | f2bs(o1);
    red[0][wave][j] = o1;
    red[1][wave][j] = o1 * o1;
    red[2][wave][j] = o2;
    red[3][wave][j] = o2 * o2;
  }
  __syncthreads();
  if (tid < 64) {
    const int st = tid >> 4, jj = tid & 15;
    float v = red[st][0][jj] + red[st][1][jj] + red[st][2][jj] + red[st][3][jj];
    const int col = (st >= 2 ? 64 : 0) + c * 16 + jj;
    float* p = statsp + (blockIdx.x & 63) * 256;
    atomicAdd(&p[col + ((st & 1) ? 128 : 0)], v);
  }
}

// Final BN+PReLU: 1024 grid-stride blocks over pair-slot chunked aggbuf.
// Prologue sums the 64 stat copies into LDS sc/sh.
__global__ __launch_bounds__(256) void k_bn_apply(const unsigned int* x32, const float* statsp,
                                                  const void* g, const void* be, const void* al,
                                                  const int* flags, void* out) {
  __shared__ float sSc[DD], sSh[DD], sAl;
  const int tid = threadIdx.x;
  const int isbf = flags[1];
  if (tid < DD) {
    float s = 0.f, q = 0.f;
#pragma unroll 8
    for (int k = 0; k < 64; k++) {
      s += statsp[k * 256 + tid];
      q += statsp[k * 256 + 128 + tid];
    }
    const float inv_n = 1.0f / NN;
    float mu = s * inv_n;
    float var = q * inv_n - mu * mu;
    float sc = rsqrtf(var + BN_EPS) * ldf(g, tid, isbf);
    sSc[tid] = sc;
    sSh[tid] = ldf(be, tid, isbf) - mu * sc;
  }
  if (tid == 0) sAl = ldf(al, 0, isbf);
  __syncthreads();
  const float alpha = sAl;
  // g2 indexes uint2 = two consecutive pair-slots (4 output values).
  for (int g2 = blockIdx.x * 256 + tid; g2 < NN * 32; g2 += gridDim.x * 256) {
    const int c = g2 / (NN * 8);           // chunk
    const int rem = g2 - c * (NN * 8);
    const int w = rem >> 3;                // node
    const int k = rem & 7;                 // slot-pair within chunk
    const int j0 = c * 16 + k * 2;         // real lo column of first slot
    const uint2 xv = ((const uint2*)x32)[g2];
    float y0 = bslo(xv.x) * sSc[j0] + sSh[j0];
    float y1 = bshi(xv.x) * sSc[j0 + 64] + sSh[j0 + 64];
    float y2 = bslo(xv.y) * sSc[j0 + 1] + sSh[j0 + 1];
    float y3 = bshi(xv.y) * sSc[j0 + 65] + sSh[j0 + 65];
    y0 = y0 > 0.f ? y0 : alpha * y0;
    y1 = y1 > 0.f ? y1 : alpha * y1;
    y2 = y2 > 0.f ? y2 : alpha * y2;
    y3 = y3 > 0.f ? y3 : alpha * y3;
    if (isbf) {
      ((unsigned int*)out)[(size_t)w * 64 + (j0 >> 1)] = (f2bs(y2) << 16) | f2bs(y0);
      ((unsigned int*)out)[(size_t)w * 64 + 32 + (j0 >> 1)] = (f2bs(y3) << 16) | f2bs(y1);
    } else {
      float2 lo = {y0, y2};
      float2 hi = {y1, y3};
      ((float2*)out)[(size_t)w * 64 + (j0 >> 1)] = lo;
      ((float2*)out)[(size_t)w * 64 + 32 + (j0 >> 1)] = hi;
    }
  }
}

extern "C" void kernel_launch(void* const* d_in, const int* in_sizes, int n_in,
                              void* d_out, int out_size, void* d_ws, size_t ws_size,
                              hipStream_t stream) {
  const void* x = d_in[0];
  const int* ei = (const int*)d_in[1];
  const void* W1 = d_in[2];
  const void* b1 = d_in[3];
  const void* g1 = d_in[4];
  const void* be1 = d_in[5];
  const void* a1 = d_in[6];
  const void* W2 = d_in[7];
  const void* b2 = d_in[8];
  const void* g2 = d_in[9];
  const void* be2 = d_in[10];
  const void* a2 = d_in[11];

  char* w = (char*)d_ws;
  float* dinv = (float*)w;                              // 200000
  int* flags = (int*)(w + 200704);                      // 8
  int* rowptr = (int*)(w + 404800);                     // 200000
  int* rowend = (int*)(w + 604816);                     // 200000
  int* tailc = (int*)(w + 805632);                      // 256
  float* stats1p = (float*)(w + 806400);                // 65536
  float* stats2p = (float*)(w + 871936);                // 65536
  int* csr_src = (int*)(w + 1048576);                   // 3612672
  unsigned int* hbuf = (unsigned int*)(w + 4718592);    // 12800000
  unsigned short* wp1 = (unsigned short*)(w + 17518592);   // 32768
  unsigned short* wp2 = (unsigned short*)(w + 17551360);   // 32768
  unsigned int* aggbuf = (unsigned int*)(w + 30056448);    // 12800000
  unsigned int* binned = (unsigned int*)(w + 42856448);  // 3612672

  const int NB_G = (NN + 127) / 128;   // 391

  hipMemsetAsync(tailc, 0, 256, stream);
  k_bin<<<dim3(256), dim3(256), 0, stream>>>(ei, (const unsigned short*)x, W1, W2,
                                             wp1, wp2, flags, tailc, binned);
  k_degfill<<<dim3(NBKT), dim3(1024), 0, stream>>>(binned, tailc, dinv, rowptr, rowend,
                                                   csr_src);

  // ---- layer 1 ----
  k_gemm<0><<<dim3(NB_G), dim3(256), 0, stream>>>(x, wp1, flags, dinv,
                                                  nullptr, nullptr, nullptr, nullptr,
                                                  stats1p, hbuf);
  k_agg<<<dim3(4 * NBAGG), dim3(256), 0, stream>>>(hbuf, dinv, rowptr, rowend, csr_src,
                                                   b1, flags, aggbuf, stats1p);

  // ---- layer 2 (BN1+PReLU fused into GEMM A-path via stats1p) ----
  k_gemm<2><<<dim3(NB_G), dim3(256), 0, stream>>>(aggbuf, wp2, flags, dinv,
                                                  stats1p, g1, be1, a1, stats2p, hbuf);
  k_agg<<<dim3(4 * NBAGG), dim3(256), 0, stream>>>(hbuf, dinv, rowptr, rowend, csr_src,
                                                   b2, flags, aggbuf, stats2p);
  k_bn_apply<<<dim3(1024), dim3(256), 0, stream>>>(aggbuf, stats2p,
                                                   g2, be2, a2, flags, d_out);
}

// Round 3
// 263.134 us; speedup vs baseline: 1.2521x; 1.2521x over previous
//
#include <hip/hip_runtime.h>
#include <hip/hip_bf16.h>

// 2-layer GCN encoder: (GCNConv -> BatchNorm1d(train) -> PReLU) x 2
// N=50000, E=800000, D=128. Inputs f32 (probed), edge_index int64 (probed),
// output f32. Internal: GEMM/agg buffers bf16, math f32.
//
// R16 = R15 with the nontemporal-store compile fix (pack uint2 -> u64).
// R15: revert R14's chunked agg (regressed: latency-bound, chunk residency
// failed). R13 whole-row gather, but uint4-wide: 16 lanes x 16B per edge ->
// one wave instruction gathers 4 edges (1KB coalesced), 16-edge unroll = 4
// independent gathers (4KB in flight, 2x R13), half the gather instructions,
// index loads coalesced. Cross-group shfl_xor(16|32) reduce. NT hints on
// aggbuf stores + csr_src loads to keep the 12.8MB hbuf gather table in L2.
//
// ws layout (bytes):
//   [0       .. +200000)   dinv f32[NN]
//   [200704  .. +8)        flags: [0]=int64?, [1]=bf16-floats?
//   [404800  .. +200000)   rowptr int[NN] (row starts, gapped CSR)
//   [604816  .. +200000)   rowend int[NN]
//   [805632  .. +256)      tailc int[64] (zeroed by memset; bucket fill counts)
//   [806400  .. +65536)    stats1p f32[64][256]
//   [871936  .. +65536)    stats2p f32[64][256]
//   [1048576 .. +3.7MB)    csr_src int[49*CAP]
//   [4718592 .. +12.8MB)   hbuf  bf16[NN*DD] packed-slot layout (dinv-scaled)
//   [17518592.. +32768)    wp1 bf16[128*128] swizzled
//   [17551360.. +32768)    wp2 bf16[128*128] swizzled
//   [30056448.. +12.8MB)   aggbuf bf16[NN*DD] row-major
//   [42856448.. +3.7MB)    binned uint[49*CAP] packed

typedef __hip_bfloat16 bf16;
typedef __attribute__((ext_vector_type(8))) short short8;   // 8 bf16 = 4 VGPR
typedef __attribute__((ext_vector_type(4))) float f32x4;    // MFMA accumulator

#define NN 50000
#define NE 800000
#define DD 128
#define BN_EPS 1e-5f
#define BIN_CHUNK 3125   // NE / 256 exactly
#define CAP 18432        // per-bucket slot capacity (72*256; mu+16sigma)
#define NBKT 49          // ceil(50000 / 1024)

__device__ __forceinline__ float b2f(bf16 v) { return __bfloat162float(v); }
__device__ __forceinline__ float ldf(const void* p, size_t idx, int isbf) {
  return isbf ? b2f(((const bf16*)p)[idx]) : ((const float*)p)[idx];
}
__device__ __forceinline__ int lde(const void* ei, size_t idx, int is64) {
  return is64 ? (int)((const long long*)ei)[idx] : ((const int*)ei)[idx];
}
__device__ __forceinline__ unsigned int f2bs(float v) {
  bf16 b = __float2bfloat16(v);
  return (unsigned int)*reinterpret_cast<unsigned short*>(&b);
}
__device__ __forceinline__ float bslo(unsigned int u) { return __uint_as_float(u << 16); }
__device__ __forceinline__ float bshi(unsigned int u) { return __uint_as_float(u & 0xFFFF0000u); }
__device__ __forceinline__ float s2f(short v) {
  return __uint_as_float(((unsigned int)(unsigned short)v) << 16);
}

// 256 blocks x 256. Per-block dtype self-probe; block 0 publishes flags;
// blocks 0..63 swizzle W1, 64..127 swizzle W2; all bin their edge chunk into
// packed binned[] at zero-based bucket counters (tailc pre-zeroed).
__global__ __launch_bounds__(256) void k_bin(const int* ei_i, const unsigned short* x16,
                                             const void* W1, const void* W2,
                                             unsigned short* wp1, unsigned short* wp2,
                                             int* flags, int* tailc, unsigned int* binned) {
  __shared__ int cnt[64], cur[64], gb[64], sflags[2];
  __shared__ unsigned int ebuf[BIN_CHUNK];  // 12.5 KB
  const int tid = threadIdx.x;
  const int bid = blockIdx.x;
  if (tid < 64) {
    unsigned long long m1 = __ballot(ei_i[2 * tid + 1] != 0);
    int ex = (x16[2 * tid] >> 7) & 0xFF;
    unsigned long long m2 = __ballot(ex >= 90 && ex <= 140);
    if (tid == 0) {
      sflags[0] = (m1 == 0ull) ? 1 : 0;
      sflags[1] = (__popcll(m2) >= 48) ? 1 : 0;
    }
    cnt[tid] = 0;
    cur[tid] = 0;
  }
  __syncthreads();
  const int is64 = sflags[0], isbf = sflags[1];
  if (bid == 0 && tid == 0) { flags[0] = is64; flags[1] = isbf; }
  if (bid < 128) {  // W swizzle side-job
    const void* W = bid < 64 ? W1 : W2;
    unsigned short* wp = bid < 64 ? wp1 : wp2;
    int idx = (bid & 63) * 256 + tid;
    int k = idx >> 7, n = idx & 127;
    wp[(k >> 3) * 1024 + n * 8 + (k & 7)] = (unsigned short)f2bs(ldf(W, idx, isbf));
  }
  const void* ei = (const void*)ei_i;
  const int e0 = bid * BIN_CHUNK;
  for (int t = tid; t < BIN_CHUNK; t += 256) {
    int s = lde(ei, (size_t)(e0 + t), is64);
    int d = lde(ei, (size_t)NE + e0 + t, is64);
    ebuf[t] = ((unsigned)s << 16) | ((unsigned)(d >> 10) << 10) | (unsigned)(d & 1023);
    atomicAdd(&cnt[d >> 10], 1);
  }
  __syncthreads();
  if (tid < 64 && cnt[tid] > 0) gb[tid] = tid * CAP + atomicAdd(&tailc[tid], cnt[tid]);
  __syncthreads();
  for (int t = tid; t < BIN_CHUNK; t += 256) {
    unsigned int u = ebuf[t];
    int b = (int)((u >> 10) & 63);
    int r = atomicAdd(&cur[b], 1);
    binned[gb[b] + r] = u;
  }
}

// Per-bucket: degree hist (LDS) -> dinv/rowptr/rowend, then exact CSR fill
// with LDS cursors. 49 blocks x 1024. packed u: s=u>>16, dlow=u&1023.
__global__ __launch_bounds__(1024) void k_degfill(const unsigned int* binned, const int* tailc,
                                                  float* dinv, int* rowptr, int* rowend,
                                                  int* csr_src) {
  __shared__ int hist[1024];
  const int b = blockIdx.x;
  const int t = threadIdx.x;
  hist[t] = 0;
  __syncthreads();
  const int eb = b * CAP, ee = eb + tailc[b];
  for (int e = eb + t; e < ee; e += 1024) atomicAdd(&hist[binned[e] & 1023], 1);
  __syncthreads();
  int h = hist[t];
  __syncthreads();
  for (int off = 1; off < 1024; off <<= 1) {  // inclusive scan
    int u = (t >= off) ? hist[t - off] : 0;
    __syncthreads();
    hist[t] += u;
    __syncthreads();
  }
  int start = eb + hist[t] - h;  // exclusive prefix, global position
  int node = b * 1024 + t;
  if (node < NN) {
    rowptr[node] = start;
    rowend[node] = start + h;
    dinv[node] = rsqrtf((float)(h + 1));  // +1 self-loop
  }
  __syncthreads();
  hist[t] = start;  // repurpose as fill cursor
  __syncthreads();
  for (int e = eb + t; e < ee; e += 1024) {
    unsigned int u = binned[e];
    int pos = atomicAdd(&hist[u & 1023], 1);
    csr_src[pos] = (int)(u >> 16);
  }
}

// MFMA GEMM. out = dinv-prescaled bf16 in packed-slot layout: row r, u32 slot
// s holds bf16 pair (col s, col s+64). W pre-swizzled (wp), raw LDS copy.
// XMODE 0: layer-1 input (probe f32/bf16). XMODE 2: aggbuf bf16 + fused BN1
// (stats from 64-copy partials statsp). Blocks 0..63 zero zstats (consumed by
// the NEXT kernel's atomics -- stream-ordered, safe).
template <int XMODE>
__global__ __launch_bounds__(256) void k_gemm(const void* in_, const unsigned short* wp,
                                              const int* flags, const float* dinv,
                                              const float* statsp, const void* g,
                                              const void* be, const void* al,
                                              float* zstats, unsigned int* out) {
  __shared__ alignas(16) short sW[16 * 128 * 8];  // 32 KB
  __shared__ float sSc[DD], sSh[DD], sAl;
  const int isbf = flags[1];
  const int tid = threadIdx.x;

  if (blockIdx.x < 64) zstats[blockIdx.x * 256 + tid] = 0.f;
  {
    const short8* src = (const short8*)wp;
    short8* dst = (short8*)sW;
#pragma unroll
    for (int i = 0; i < 8; i++) dst[tid + i * 256] = src[tid + i * 256];
  }
  if (XMODE == 2) {
    if (tid < DD) {
      float s = 0.f, q = 0.f;
#pragma unroll 8
      for (int k = 0; k < 64; k++) {
        s += statsp[k * 256 + tid];
        q += statsp[k * 256 + 128 + tid];
      }
      const float inv_n = 1.0f / NN;
      float mu = s * inv_n;
      float var = q * inv_n - mu * mu;
      float sc = rsqrtf(var + BN_EPS) * ldf(g, tid, isbf);
      sSc[tid] = sc;
      sSh[tid] = ldf(be, tid, isbf) - mu * sc;
    }
    if (tid == 0) sAl = ldf(al, 0, isbf);
  }
  __syncthreads();

  const int wave = tid >> 6;
  const int lane = tid & 63;
  const int quad = lane >> 4;
  const int m16 = lane & 15;
  const int r0 = blockIdx.x * 128 + wave * 32;

  f32x4 acc[2][8];
#pragma unroll
  for (int t = 0; t < 2; t++)
#pragma unroll
    for (int n = 0; n < 8; n++) acc[t][n] = (f32x4){0.f, 0.f, 0.f, 0.f};

#pragma unroll
  for (int q = 0; q < 4; q++) {
    const int kq = q * 32 + quad * 8;
    short8 af[2];
#pragma unroll
    for (int t = 0; t < 2; t++) {
      int row = r0 + t * 16 + m16;
      row = row < NN ? row : NN - 1;  // clamp; garbage rows never stored
      if (XMODE == 2) {
        short8 raw = *(const short8*)((const short*)in_ + (size_t)row * DD + kq);
        short8 f;
#pragma unroll
        for (int jj = 0; jj < 8; jj++) {
          float y = s2f(raw[jj]);
          y = y * sSc[kq + jj] + sSh[kq + jj];
          y = y > 0.f ? y : sAl * y;
          f[jj] = (short)f2bs(y);
        }
        af[t] = f;
      } else if (isbf) {
        af[t] = *(const short8*)((const short*)in_ + (size_t)row * DD + kq);
      } else {
        const float* ap = (const float*)in_ + (size_t)row * DD + kq;
        const float4 u0 = *(const float4*)ap;
        const float4 u1 = *(const float4*)(ap + 4);
        float v[8] = {u0.x, u0.y, u0.z, u0.w, u1.x, u1.y, u1.z, u1.w};
        short8 f;
#pragma unroll
        for (int jj = 0; jj < 8; jj++) f[jj] = (short)f2bs(v[jj]);
        af[t] = f;
      }
    }
    const int c = q * 4 + quad;
    const short* bp = sW + c * 1024 + m16 * 8;
#pragma unroll
    for (int n = 0; n < 8; n++) {
      const short8 bfrag = *(const short8*)(bp + n * 128);
      acc[0][n] = __builtin_amdgcn_mfma_f32_16x16x32_bf16(af[0], bfrag, acc[0][n], 0, 0, 0);
      acc[1][n] = __builtin_amdgcn_mfma_f32_16x16x32_bf16(af[1], bfrag, acc[1][n], 0, 0, 0);
    }
  }

#pragma unroll
  for (int t = 0; t < 2; t++)
#pragma unroll
    for (int r = 0; r < 4; r++) {
      int row = r0 + t * 16 + quad * 4 + r;
      if (row < NN) {
        float di = dinv[row];
        unsigned int* orow = out + (size_t)row * 64;
#pragma unroll
        for (int n = 0; n < 4; n++) {
          unsigned int p = (f2bs(di * acc[t][n + 4][r]) << 16) | f2bs(di * acc[t][n][r]);
          orow[n * 16 + m16] = p;
        }
      }
    }
}

// One wave per node (12500 blocks = 50000 waves). uint4-wide gather: 16 lanes
// per edge (lane j covers u32 slots 4j..4j+3), one wave instruction = 4 edges
// (1KB coalesced). 16-edge unroll = 4 independent gathers in flight. Groups
// folded by shfl_xor(16|32). NT on csr_src loads + aggbuf stores (read/write
// once) to keep the 12.8MB hbuf gather table in L2.
__global__ __launch_bounds__(256) void k_agg(const unsigned int* hs, const float* dinv,
                                             const int* rowptr, const int* rowend,
                                             const int* csr_src, const void* bias,
                                             const int* flags, unsigned short* out,
                                             float* statsp) {
  const int tid = threadIdx.x;
  const int w = (blockIdx.x * 256 + tid) >> 6;   // node; 12500*4 == NN
  const int lane = tid & 63;
  const int grp = lane >> 4;                     // edge sub-group 0..3
  const int j = lane & 15;                       // uint4 index within row
  const uint4* hs4 = (const uint4*)hs;           // row stride = 16 uint4
  const float dd_ = dinv[w];
  const int isbf = flags[1];

  float ax[4] = {0.f, 0.f, 0.f, 0.f};
  float ay[4] = {0.f, 0.f, 0.f, 0.f};
  if (grp == 0) {  // self-loop counted once
    const uint4 own = hs4[(size_t)w * 16 + j];
    ax[0] = bslo(own.x); ay[0] = bshi(own.x);
    ax[1] = bslo(own.y); ay[1] = bshi(own.y);
    ax[2] = bslo(own.z); ay[2] = bshi(own.z);
    ax[3] = bslo(own.w); ay[3] = bshi(own.w);
  }

#define ACC4(v)                                              \
  do {                                                       \
    ax[0] += bslo((v).x); ay[0] += bshi((v).x);              \
    ax[1] += bslo((v).y); ay[1] += bshi((v).y);              \
    ax[2] += bslo((v).z); ay[2] += bshi((v).z);              \
    ax[3] += bslo((v).w); ay[3] += bshi((v).w);              \
  } while (0)

  int e = rowptr[w];
  const int e1 = rowend[w];
  for (; e + 16 <= e1; e += 16) {
    const int s0 = __builtin_nontemporal_load(&csr_src[e + grp]);
    const int s1 = __builtin_nontemporal_load(&csr_src[e + 4 + grp]);
    const int s2 = __builtin_nontemporal_load(&csr_src[e + 8 + grp]);
    const int s3 = __builtin_nontemporal_load(&csr_src[e + 12 + grp]);
    const uint4 v0 = hs4[(size_t)s0 * 16 + j];
    const uint4 v1 = hs4[(size_t)s1 * 16 + j];
    const uint4 v2 = hs4[(size_t)s2 * 16 + j];
    const uint4 v3 = hs4[(size_t)s3 * 16 + j];
    ACC4(v0); ACC4(v1); ACC4(v2); ACC4(v3);
  }
  for (; e + 8 <= e1; e += 8) {
    const int s0 = __builtin_nontemporal_load(&csr_src[e + grp]);
    const int s1 = __builtin_nontemporal_load(&csr_src[e + 4 + grp]);
    const uint4 v0 = hs4[(size_t)s0 * 16 + j];
    const uint4 v1 = hs4[(size_t)s1 * 16 + j];
    ACC4(v0); ACC4(v1);
  }
  if (e + 4 <= e1) {
    const int s0 = __builtin_nontemporal_load(&csr_src[e + grp]);
    const uint4 v0 = hs4[(size_t)s0 * 16 + j];
    ACC4(v0);
    e += 4;
  }
  if (grp < e1 - e) {  // tail 0..3 edges
    const int s0 = __builtin_nontemporal_load(&csr_src[e + grp]);
    const uint4 v0 = hs4[(size_t)s0 * 16 + j];
    ACC4(v0);
  }
#undef ACC4

  // fold the 4 edge-groups: butterfly over lane bits 4,5
#pragma unroll
  for (int u = 0; u < 4; u++) {
    ax[u] += __shfl_xor(ax[u], 16);
    ax[u] += __shfl_xor(ax[u], 32);
    ay[u] += __shfl_xor(ay[u], 16);
    ay[u] += __shfl_xor(ay[u], 32);
  }

  float o1[4], o2[4];
#pragma unroll
  for (int u = 0; u < 4; u++) {
    const int cc = 4 * j + u;
    o1[u] = dd_ * ax[u] + ldf(bias, cc, isbf);
    o2[u] = dd_ * ay[u] + ldf(bias, cc + 64, isbf);
  }

  __shared__ float rs1[4][64], rq1[4][64], rs2[4][64], rq2[4][64];  // 4 KB
  const int wv = tid >> 6;
  if (grp == 0) {
    unsigned long long p1 =
        ((unsigned long long)((f2bs(o1[3]) << 16) | f2bs(o1[2])) << 32) |
        (unsigned long long)((f2bs(o1[1]) << 16) | f2bs(o1[0]));
    unsigned long long p2 =
        ((unsigned long long)((f2bs(o2[3]) << 16) | f2bs(o2[2])) << 32) |
        (unsigned long long)((f2bs(o2[1]) << 16) | f2bs(o2[0]));
    unsigned long long* o64 = (unsigned long long*)(out + (size_t)w * DD);
    __builtin_nontemporal_store(p1, &o64[j]);
    __builtin_nontemporal_store(p2, &o64[16 + j]);
#pragma unroll
    for (int u = 0; u < 4; u++) {
      rs1[wv][4 * j + u] = o1[u];
      rq1[wv][4 * j + u] = o1[u] * o1[u];
      rs2[wv][4 * j + u] = o2[u];
      rq2[wv][4 * j + u] = o2[u] * o2[u];
    }
  }
  __syncthreads();
  {
    const int col = tid & 63, sel = tid >> 6;
    const float* rr = sel == 0 ? &rs1[0][0] : sel == 1 ? &rs2[0][0]
                    : sel == 2 ? &rq1[0][0] : &rq2[0][0];
    const float v = rr[col] + rr[64 + col] + rr[128 + col] + rr[192 + col];
    float* p = statsp + (blockIdx.x & 63) * 256;
    atomicAdd(&p[sel * 64 + col], v);
  }
}

// Final BN+PReLU: 1024 grid-stride blocks. Prologue sums the 64 stat copies
// into LDS sc/sh (one rsqrt per column per block, not per element).
__global__ __launch_bounds__(256) void k_bn_apply(const unsigned int* x32, const float* statsp,
                                                  const void* g, const void* be, const void* al,
                                                  const int* flags, void* out) {
  __shared__ float sSc[DD], sSh[DD], sAl;
  const int tid = threadIdx.x;
  const int isbf = flags[1];
  if (tid < DD) {
    float s = 0.f, q = 0.f;
#pragma unroll 8
    for (int k = 0; k < 64; k++) {
      s += statsp[k * 256 + tid];
      q += statsp[k * 256 + 128 + tid];
    }
    const float inv_n = 1.0f / NN;
    float mu = s * inv_n;
    float var = q * inv_n - mu * mu;
    float sc = rsqrtf(var + BN_EPS) * ldf(g, tid, isbf);
    sSc[tid] = sc;
    sSh[tid] = ldf(be, tid, isbf) - mu * sc;
  }
  if (tid == 0) sAl = ldf(al, 0, isbf);
  __syncthreads();
  const float alpha = sAl;
  for (int i4 = blockIdx.x * 256 + tid; i4 < NN * 32; i4 += gridDim.x * 256) {
    int jq = (i4 & 31) * 4;
    const uint2 xv = ((const uint2*)x32)[i4];
    float xa[4] = {bslo(xv.x), bshi(xv.x), bslo(xv.y), bshi(xv.y)};
    float y[4];
#pragma unroll
    for (int u = 0; u < 4; u++) {
      int j = jq + u;
      float v = xa[u] * sSc[j] + sSh[j];
      y[u] = v > 0.f ? v : alpha * v;
    }
    if (isbf) {
      uint2 o;
      o.x = (f2bs(y[1]) << 16) | f2bs(y[0]);
      o.y = (f2bs(y[3]) << 16) | f2bs(y[2]);
      ((uint2*)out)[i4] = o;
    } else {
      float4 o = {y[0], y[1], y[2], y[3]};
      ((float4*)out)[i4] = o;
    }
  }
}

extern "C" void kernel_launch(void* const* d_in, const int* in_sizes, int n_in,
                              void* d_out, int out_size, void* d_ws, size_t ws_size,
                              hipStream_t stream) {
  const void* x = d_in[0];
  const int* ei = (const int*)d_in[1];
  const void* W1 = d_in[2];
  const void* b1 = d_in[3];
  const void* g1 = d_in[4];
  const void* be1 = d_in[5];
  const void* a1 = d_in[6];
  const void* W2 = d_in[7];
  const void* b2 = d_in[8];
  const void* g2 = d_in[9];
  const void* be2 = d_in[10];
  const void* a2 = d_in[11];

  char* w = (char*)d_ws;
  float* dinv = (float*)w;                              // 200000
  int* flags = (int*)(w + 200704);                      // 8
  int* rowptr = (int*)(w + 404800);                     // 200000
  int* rowend = (int*)(w + 604816);                     // 200000
  int* tailc = (int*)(w + 805632);                      // 256
  float* stats1p = (float*)(w + 806400);                // 65536
  float* stats2p = (float*)(w + 871936);                // 65536
  int* csr_src = (int*)(w + 1048576);                   // 3612672
  unsigned int* hbuf = (unsigned int*)(w + 4718592);    // 12800000
  unsigned short* wp1 = (unsigned short*)(w + 17518592);   // 32768
  unsigned short* wp2 = (unsigned short*)(w + 17551360);   // 32768
  unsigned short* aggbuf = (unsigned short*)(w + 30056448);  // 12800000
  unsigned int* binned = (unsigned int*)(w + 42856448);  // 3612672

  const int NB_G = (NN + 127) / 128;   // 391
  const int NB_W = NN * 64 / 256;      // 12500

  hipMemsetAsync(tailc, 0, 256, stream);
  k_bin<<<dim3(256), dim3(256), 0, stream>>>(ei, (const unsigned short*)x, W1, W2,
                                             wp1, wp2, flags, tailc, binned);
  k_degfill<<<dim3(NBKT), dim3(1024), 0, stream>>>(binned, tailc, dinv, rowptr, rowend,
                                                   csr_src);

  // ---- layer 1 ----
  k_gemm<0><<<dim3(NB_G), dim3(256), 0, stream>>>(x, wp1, flags, dinv,
                                                  nullptr, nullptr, nullptr, nullptr,
                                                  stats1p, hbuf);
  k_agg<<<dim3(NB_W), dim3(256), 0, stream>>>(hbuf, dinv, rowptr, rowend, csr_src,
                                              b1, flags, aggbuf, stats1p);

  // ---- layer 2 (BN1+PReLU fused into GEMM A-path via stats1p) ----
  k_gemm<2><<<dim3(NB_G), dim3(256), 0, stream>>>(aggbuf, wp2, flags, dinv,
                                                  stats1p, g1, be1, a1, stats2p, hbuf);
  k_agg<<<dim3(NB_W), dim3(256), 0, stream>>>(hbuf, dinv, rowptr, rowend, csr_src,
                                              b2, flags, aggbuf, stats2p);
  k_bn_apply<<<dim3(1024), dim3(256), 0, stream>>>((const unsigned int*)aggbuf, stats2p,
                                                   g2, be2, a2, flags, d_out);
}

// Round 4
// 228.865 us; speedup vs baseline: 1.4396x; 1.1497x over previous
//
#include <hip/hip_runtime.h>
#include <hip/hip_bf16.h>

// 2-layer GCN encoder: (GCNConv -> BatchNorm1d(train) -> PReLU) x 2
// N=50000, E=800000, D=128. Inputs f32 (probed), edge_index int64 (probed),
// output f32. Internal: GEMM/agg buffers bf16, math f32.
//
// R17: back to R13 agg structure (one wave per node, 64-lane full-row
// gather, uniform edge indices) with the scalar path made explicit:
// rowptr/rowend go through readfirstlane -> SGPR, so index loads hit the
// scalar pipe (s_load; lgkmcnt not vmcnt), loop control is SALU, and each
// gather costs 1 dest VGPR -> 16-deep in-flight gather window (2x R13's 8)
// at no occupancy cost. No NT hints anywhere (R16's NT on the index loads
// sat on the dependent chain and regressed).
//
// ws layout (bytes):
//   [0       .. +200000)   dinv f32[NN]
//   [200704  .. +8)        flags: [0]=int64?, [1]=bf16-floats?
//   [404800  .. +200000)   rowptr int[NN] (row starts, gapped CSR)
//   [604816  .. +200000)   rowend int[NN]
//   [805632  .. +256)      tailc int[64] (zeroed by memset; bucket fill counts)
//   [806400  .. +65536)    stats1p f32[64][256]
//   [871936  .. +65536)    stats2p f32[64][256]
//   [1048576 .. +3.7MB)    csr_src int[49*CAP]
//   [4718592 .. +12.8MB)   hbuf  bf16[NN*DD] packed-slot layout (dinv-scaled)
//   [17518592.. +32768)    wp1 bf16[128*128] swizzled
//   [17551360.. +32768)    wp2 bf16[128*128] swizzled
//   [30056448.. +12.8MB)   aggbuf bf16[NN*DD] row-major
//   [42856448.. +3.7MB)    binned uint[49*CAP] packed

typedef __hip_bfloat16 bf16;
typedef __attribute__((ext_vector_type(8))) short short8;   // 8 bf16 = 4 VGPR
typedef __attribute__((ext_vector_type(4))) float f32x4;    // MFMA accumulator

#define NN 50000
#define NE 800000
#define DD 128
#define BN_EPS 1e-5f
#define BIN_CHUNK 3125   // NE / 256 exactly
#define CAP 18432        // per-bucket slot capacity (72*256; mu+16sigma)
#define NBKT 49          // ceil(50000 / 1024)

__device__ __forceinline__ float b2f(bf16 v) { return __bfloat162float(v); }
__device__ __forceinline__ float ldf(const void* p, size_t idx, int isbf) {
  return isbf ? b2f(((const bf16*)p)[idx]) : ((const float*)p)[idx];
}
__device__ __forceinline__ int lde(const void* ei, size_t idx, int is64) {
  return is64 ? (int)((const long long*)ei)[idx] : ((const int*)ei)[idx];
}
__device__ __forceinline__ unsigned int f2bs(float v) {
  bf16 b = __float2bfloat16(v);
  return (unsigned int)*reinterpret_cast<unsigned short*>(&b);
}
__device__ __forceinline__ float bslo(unsigned int u) { return __uint_as_float(u << 16); }
__device__ __forceinline__ float bshi(unsigned int u) { return __uint_as_float(u & 0xFFFF0000u); }
__device__ __forceinline__ float s2f(short v) {
  return __uint_as_float(((unsigned int)(unsigned short)v) << 16);
}

// 256 blocks x 256. Per-block dtype self-probe; block 0 publishes flags;
// blocks 0..63 swizzle W1, 64..127 swizzle W2; all bin their edge chunk into
// packed binned[] at zero-based bucket counters (tailc pre-zeroed).
__global__ __launch_bounds__(256) void k_bin(const int* ei_i, const unsigned short* x16,
                                             const void* W1, const void* W2,
                                             unsigned short* wp1, unsigned short* wp2,
                                             int* flags, int* tailc, unsigned int* binned) {
  __shared__ int cnt[64], cur[64], gb[64], sflags[2];
  __shared__ unsigned int ebuf[BIN_CHUNK];  // 12.5 KB
  const int tid = threadIdx.x;
  const int bid = blockIdx.x;
  if (tid < 64) {
    unsigned long long m1 = __ballot(ei_i[2 * tid + 1] != 0);
    int ex = (x16[2 * tid] >> 7) & 0xFF;
    unsigned long long m2 = __ballot(ex >= 90 && ex <= 140);
    if (tid == 0) {
      sflags[0] = (m1 == 0ull) ? 1 : 0;
      sflags[1] = (__popcll(m2) >= 48) ? 1 : 0;
    }
    cnt[tid] = 0;
    cur[tid] = 0;
  }
  __syncthreads();
  const int is64 = sflags[0], isbf = sflags[1];
  if (bid == 0 && tid == 0) { flags[0] = is64; flags[1] = isbf; }
  if (bid < 128) {  // W swizzle side-job
    const void* W = bid < 64 ? W1 : W2;
    unsigned short* wp = bid < 64 ? wp1 : wp2;
    int idx = (bid & 63) * 256 + tid;
    int k = idx >> 7, n = idx & 127;
    wp[(k >> 3) * 1024 + n * 8 + (k & 7)] = (unsigned short)f2bs(ldf(W, idx, isbf));
  }
  const void* ei = (const void*)ei_i;
  const int e0 = bid * BIN_CHUNK;
  for (int t = tid; t < BIN_CHUNK; t += 256) {
    int s = lde(ei, (size_t)(e0 + t), is64);
    int d = lde(ei, (size_t)NE + e0 + t, is64);
    ebuf[t] = ((unsigned)s << 16) | ((unsigned)(d >> 10) << 10) | (unsigned)(d & 1023);
    atomicAdd(&cnt[d >> 10], 1);
  }
  __syncthreads();
  if (tid < 64 && cnt[tid] > 0) gb[tid] = tid * CAP + atomicAdd(&tailc[tid], cnt[tid]);
  __syncthreads();
  for (int t = tid; t < BIN_CHUNK; t += 256) {
    unsigned int u = ebuf[t];
    int b = (int)((u >> 10) & 63);
    int r = atomicAdd(&cur[b], 1);
    binned[gb[b] + r] = u;
  }
}

// Per-bucket: degree hist (LDS) -> dinv/rowptr/rowend, then exact CSR fill
// with LDS cursors. 49 blocks x 1024. packed u: s=u>>16, dlow=u&1023.
__global__ __launch_bounds__(1024) void k_degfill(const unsigned int* binned, const int* tailc,
                                                  float* dinv, int* rowptr, int* rowend,
                                                  int* csr_src) {
  __shared__ int hist[1024];
  const int b = blockIdx.x;
  const int t = threadIdx.x;
  hist[t] = 0;
  __syncthreads();
  const int eb = b * CAP, ee = eb + tailc[b];
  for (int e = eb + t; e < ee; e += 1024) atomicAdd(&hist[binned[e] & 1023], 1);
  __syncthreads();
  int h = hist[t];
  __syncthreads();
  for (int off = 1; off < 1024; off <<= 1) {  // inclusive scan
    int u = (t >= off) ? hist[t - off] : 0;
    __syncthreads();
    hist[t] += u;
    __syncthreads();
  }
  int start = eb + hist[t] - h;  // exclusive prefix, global position
  int node = b * 1024 + t;
  if (node < NN) {
    rowptr[node] = start;
    rowend[node] = start + h;
    dinv[node] = rsqrtf((float)(h + 1));  // +1 self-loop
  }
  __syncthreads();
  hist[t] = start;  // repurpose as fill cursor
  __syncthreads();
  for (int e = eb + t; e < ee; e += 1024) {
    unsigned int u = binned[e];
    int pos = atomicAdd(&hist[u & 1023], 1);
    csr_src[pos] = (int)(u >> 16);
  }
}

// MFMA GEMM. out = dinv-prescaled bf16 in packed-slot layout: row r, u32 slot
// s holds bf16 pair (col s, col s+64). W pre-swizzled (wp), raw LDS copy.
// XMODE 0: layer-1 input (probe f32/bf16). XMODE 2: aggbuf bf16 + fused BN1
// (stats from 64-copy partials statsp). Blocks 0..63 zero zstats (consumed by
// the NEXT kernel's atomics -- stream-ordered, safe).
template <int XMODE>
__global__ __launch_bounds__(256) void k_gemm(const void* in_, const unsigned short* wp,
                                              const int* flags, const float* dinv,
                                              const float* statsp, const void* g,
                                              const void* be, const void* al,
                                              float* zstats, unsigned int* out) {
  __shared__ alignas(16) short sW[16 * 128 * 8];  // 32 KB
  __shared__ float sSc[DD], sSh[DD], sAl;
  const int isbf = flags[1];
  const int tid = threadIdx.x;

  if (blockIdx.x < 64) zstats[blockIdx.x * 256 + tid] = 0.f;
  {
    const short8* src = (const short8*)wp;
    short8* dst = (short8*)sW;
#pragma unroll
    for (int i = 0; i < 8; i++) dst[tid + i * 256] = src[tid + i * 256];
  }
  if (XMODE == 2) {
    if (tid < DD) {
      float s = 0.f, q = 0.f;
#pragma unroll 8
      for (int k = 0; k < 64; k++) {
        s += statsp[k * 256 + tid];
        q += statsp[k * 256 + 128 + tid];
      }
      const float inv_n = 1.0f / NN;
      float mu = s * inv_n;
      float var = q * inv_n - mu * mu;
      float sc = rsqrtf(var + BN_EPS) * ldf(g, tid, isbf);
      sSc[tid] = sc;
      sSh[tid] = ldf(be, tid, isbf) - mu * sc;
    }
    if (tid == 0) sAl = ldf(al, 0, isbf);
  }
  __syncthreads();

  const int wave = tid >> 6;
  const int lane = tid & 63;
  const int quad = lane >> 4;
  const int m16 = lane & 15;
  const int r0 = blockIdx.x * 128 + wave * 32;

  f32x4 acc[2][8];
#pragma unroll
  for (int t = 0; t < 2; t++)
#pragma unroll
    for (int n = 0; n < 8; n++) acc[t][n] = (f32x4){0.f, 0.f, 0.f, 0.f};

#pragma unroll
  for (int q = 0; q < 4; q++) {
    const int kq = q * 32 + quad * 8;
    short8 af[2];
#pragma unroll
    for (int t = 0; t < 2; t++) {
      int row = r0 + t * 16 + m16;
      row = row < NN ? row : NN - 1;  // clamp; garbage rows never stored
      if (XMODE == 2) {
        short8 raw = *(const short8*)((const short*)in_ + (size_t)row * DD + kq);
        short8 f;
#pragma unroll
        for (int jj = 0; jj < 8; jj++) {
          float y = s2f(raw[jj]);
          y = y * sSc[kq + jj] + sSh[kq + jj];
          y = y > 0.f ? y : sAl * y;
          f[jj] = (short)f2bs(y);
        }
        af[t] = f;
      } else if (isbf) {
        af[t] = *(const short8*)((const short*)in_ + (size_t)row * DD + kq);
      } else {
        const float* ap = (const float*)in_ + (size_t)row * DD + kq;
        const float4 u0 = *(const float4*)ap;
        const float4 u1 = *(const float4*)(ap + 4);
        float v[8] = {u0.x, u0.y, u0.z, u0.w, u1.x, u1.y, u1.z, u1.w};
        short8 f;
#pragma unroll
        for (int jj = 0; jj < 8; jj++) f[jj] = (short)f2bs(v[jj]);
        af[t] = f;
      }
    }
    const int c = q * 4 + quad;
    const short* bp = sW + c * 1024 + m16 * 8;
#pragma unroll
    for (int n = 0; n < 8; n++) {
      const short8 bfrag = *(const short8*)(bp + n * 128);
      acc[0][n] = __builtin_amdgcn_mfma_f32_16x16x32_bf16(af[0], bfrag, acc[0][n], 0, 0, 0);
      acc[1][n] = __builtin_amdgcn_mfma_f32_16x16x32_bf16(af[1], bfrag, acc[1][n], 0, 0, 0);
    }
  }

#pragma unroll
  for (int t = 0; t < 2; t++)
#pragma unroll
    for (int r = 0; r < 4; r++) {
      int row = r0 + t * 16 + quad * 4 + r;
      if (row < NN) {
        float di = dinv[row];
        unsigned int* orow = out + (size_t)row * 64;
#pragma unroll
        for (int n = 0; n < 4; n++) {
          unsigned int p = (f2bs(di * acc[t][n + 4][r]) << 16) | f2bs(di * acc[t][n][r]);
          orow[n * 16 + m16] = p;
        }
      }
    }
}

// One wave per node (12500 blocks = 50000 waves exactly). Row range
// [rowptr[w], rowend[w]) in the gapped CSR, forced into SGPRs via
// readfirstlane: index loads take the scalar pipe (s_load), loop control is
// SALU, each gather costs 1 dest VGPR. 16-deep gather window, then 4, then 1.
__global__ __launch_bounds__(256) void k_agg(const unsigned int* hs, const float* dinv,
                                             const int* rowptr, const int* rowend,
                                             const int* csr_src, const void* bias,
                                             const int* flags, unsigned short* out,
                                             float* statsp) {
  const int tid = threadIdx.x;
  const int w = (blockIdx.x * 256 + tid) >> 6;   // never >= NN (12500*4 == NN)
  const int lane = tid & 63;
  const float dd_ = dinv[w];
  unsigned int hv = hs[(size_t)w * 64 + lane];
  float ax = bslo(hv), ay = bshi(hv);
  int e = __builtin_amdgcn_readfirstlane(rowptr[w]);
  const int e1 = __builtin_amdgcn_readfirstlane(rowend[w]);

  for (; e + 16 <= e1; e += 16) {
    int s[16];
#pragma unroll
    for (int k = 0; k < 16; k++) s[k] = csr_src[e + k];
    unsigned int v[16];
#pragma unroll
    for (int k = 0; k < 16; k++) v[k] = hs[(size_t)s[k] * 64 + lane];
#pragma unroll
    for (int k = 0; k < 16; k++) { ax += bslo(v[k]); ay += bshi(v[k]); }
  }
  for (; e + 4 <= e1; e += 4) {
    int s[4];
#pragma unroll
    for (int k = 0; k < 4; k++) s[k] = csr_src[e + k];
    unsigned int v[4];
#pragma unroll
    for (int k = 0; k < 4; k++) v[k] = hs[(size_t)s[k] * 64 + lane];
#pragma unroll
    for (int k = 0; k < 4; k++) { ax += bslo(v[k]); ay += bshi(v[k]); }
  }
  for (; e < e1; e++) {
    unsigned int v0 = hs[(size_t)csr_src[e] * 64 + lane];
    ax += bslo(v0);
    ay += bshi(v0);
  }

  int isbf = flags[1];
  float o1 = dd_ * ax + ldf(bias, lane, isbf);
  float o2 = dd_ * ay + ldf(bias, lane + 64, isbf);
  unsigned short* orow = out + (size_t)w * DD;
  orow[lane] = (unsigned short)f2bs(o1);
  orow[lane + 64] = (unsigned short)f2bs(o2);

  __shared__ float rs1[256], rq1[256], rs2[256], rq2[256];
  rs1[tid] = o1; rq1[tid] = o1 * o1;
  rs2[tid] = o2; rq2[tid] = o2 * o2;
  __syncthreads();
  float* p = statsp + (blockIdx.x & 63) * 256;
  if (tid < 64) {  // col tid
    float s = rs1[tid] + rs1[tid + 64] + rs1[tid + 128] + rs1[tid + 192];
    float q = rq1[tid] + rq1[tid + 64] + rq1[tid + 128] + rq1[tid + 192];
    atomicAdd(&p[tid], s);
    atomicAdd(&p[128 + tid], q);
  } else if (tid < 128) {  // col tid (= 64 + lane)
    int l = tid - 64;
    float s = rs2[l] + rs2[l + 64] + rs2[l + 128] + rs2[l + 192];
    float q = rq2[l] + rq2[l + 64] + rq2[l + 128] + rq2[l + 192];
    atomicAdd(&p[tid], s);
    atomicAdd(&p[128 + tid], q);
  }
}

// Final BN+PReLU: 1024 grid-stride blocks. Prologue sums the 64 stat copies
// into LDS sc/sh (one rsqrt per column per block, not per element).
__global__ __launch_bounds__(256) void k_bn_apply(const unsigned int* x32, const float* statsp,
                                                  const void* g, const void* be, const void* al,
                                                  const int* flags, void* out) {
  __shared__ float sSc[DD], sSh[DD], sAl;
  const int tid = threadIdx.x;
  const int isbf = flags[1];
  if (tid < DD) {
    float s = 0.f, q = 0.f;
#pragma unroll 8
    for (int k = 0; k < 64; k++) {
      s += statsp[k * 256 + tid];
      q += statsp[k * 256 + 128 + tid];
    }
    const float inv_n = 1.0f / NN;
    float mu = s * inv_n;
    float var = q * inv_n - mu * mu;
    float sc = rsqrtf(var + BN_EPS) * ldf(g, tid, isbf);
    sSc[tid] = sc;
    sSh[tid] = ldf(be, tid, isbf) - mu * sc;
  }
  if (tid == 0) sAl = ldf(al, 0, isbf);
  __syncthreads();
  const float alpha = sAl;
  for (int i4 = blockIdx.x * 256 + tid; i4 < NN * 32; i4 += gridDim.x * 256) {
    int jq = (i4 & 31) * 4;
    const uint2 xv = ((const uint2*)x32)[i4];
    float xa[4] = {bslo(xv.x), bshi(xv.x), bslo(xv.y), bshi(xv.y)};
    float y[4];
#pragma unroll
    for (int u = 0; u < 4; u++) {
      int j = jq + u;
      float v = xa[u] * sSc[j] + sSh[j];
      y[u] = v > 0.f ? v : alpha * v;
    }
    if (isbf) {
      uint2 o;
      o.x = (f2bs(y[1]) << 16) | f2bs(y[0]);
      o.y = (f2bs(y[3]) << 16) | f2bs(y[2]);
      ((uint2*)out)[i4] = o;
    } else {
      float4 o = {y[0], y[1], y[2], y[3]};
      ((float4*)out)[i4] = o;
    }
  }
}

extern "C" void kernel_launch(void* const* d_in, const int* in_sizes, int n_in,
                              void* d_out, int out_size, void* d_ws, size_t ws_size,
                              hipStream_t stream) {
  const void* x = d_in[0];
  const int* ei = (const int*)d_in[1];
  const void* W1 = d_in[2];
  const void* b1 = d_in[3];
  const void* g1 = d_in[4];
  const void* be1 = d_in[5];
  const void* a1 = d_in[6];
  const void* W2 = d_in[7];
  const void* b2 = d_in[8];
  const void* g2 = d_in[9];
  const void* be2 = d_in[10];
  const void* a2 = d_in[11];

  char* w = (char*)d_ws;
  float* dinv = (float*)w;                              // 200000
  int* flags = (int*)(w + 200704);                      // 8
  int* rowptr = (int*)(w + 404800);                     // 200000
  int* rowend = (int*)(w + 604816);                     // 200000
  int* tailc = (int*)(w + 805632);                      // 256
  float* stats1p = (float*)(w + 806400);                // 65536
  float* stats2p = (float*)(w + 871936);                // 65536
  int* csr_src = (int*)(w + 1048576);                   // 3612672
  unsigned int* hbuf = (unsigned int*)(w + 4718592);    // 12800000
  unsigned short* wp1 = (unsigned short*)(w + 17518592);   // 32768
  unsigned short* wp2 = (unsigned short*)(w + 17551360);   // 32768
  unsigned short* aggbuf = (unsigned short*)(w + 30056448);  // 12800000
  unsigned int* binned = (unsigned int*)(w + 42856448);  // 3612672

  const int NB_G = (NN + 127) / 128;   // 391
  const int NB_W = NN * 64 / 256;      // 12500

  hipMemsetAsync(tailc, 0, 256, stream);
  k_bin<<<dim3(256), dim3(256), 0, stream>>>(ei, (const unsigned short*)x, W1, W2,
                                             wp1, wp2, flags, tailc, binned);
  k_degfill<<<dim3(NBKT), dim3(1024), 0, stream>>>(binned, tailc, dinv, rowptr, rowend,
                                                   csr_src);

  // ---- layer 1 ----
  k_gemm<0><<<dim3(NB_G), dim3(256), 0, stream>>>(x, wp1, flags, dinv,
                                                  nullptr, nullptr, nullptr, nullptr,
                                                  stats1p, hbuf);
  k_agg<<<dim3(NB_W), dim3(256), 0, stream>>>(hbuf, dinv, rowptr, rowend, csr_src,
                                              b1, flags, aggbuf, stats1p);

  // ---- layer 2 (BN1+PReLU fused into GEMM A-path via stats1p) ----
  k_gemm<2><<<dim3(NB_G), dim3(256), 0, stream>>>(aggbuf, wp2, flags, dinv,
                                                  stats1p, g1, be1, a1, stats2p, hbuf);
  k_agg<<<dim3(NB_W), dim3(256), 0, stream>>>(hbuf, dinv, rowptr, rowend, csr_src,
                                              b2, flags, aggbuf, stats2p);
  k_bn_apply<<<dim3(1024), dim3(256), 0, stream>>>((const unsigned int*)aggbuf, stats2p,
                                                   g2, be2, a2, flags, d_out);
}

// Round 5
// 224.148 us; speedup vs baseline: 1.4699x; 1.0210x over previous
//
#include <hip/hip_runtime.h>
#include <hip/hip_bf16.h>

// 2-layer GCN encoder: (GCNConv -> BatchNorm1d(train) -> PReLU) x 2
// N=50000, E=800000, D=128. Inputs f32 (probed), edge_index int64 (probed),
// output f32. Internal: GEMM/agg buffers bf16, math f32.
//
// R18: k_gemm tile 128 -> 64 rows/block (391 -> 782 blocks). At 391 blocks
// the grid was 1.53 blocks/CU: half the CUs idled in the second dispatch
// round (tail), and ~6 waves/CU couldn't hide A-load latency. 64-row blocks
// double the grid, halve per-wave acc VGPRs, keep LDS 32KB (5 blocks/CU
// resident) -> smoother tail + real load overlap. Weight-staging L2 traffic
// doubles (25MB aggregate, negligible). k_agg stays R17 (scalar-pipe 16-deep
// gather window, TLP-saturated at ~3TB/s LLC random-read).
//
// ws layout (bytes):
//   [0       .. +200000)   dinv f32[NN]
//   [200704  .. +8)        flags: [0]=int64?, [1]=bf16-floats?
//   [404800  .. +200000)   rowptr int[NN] (row starts, gapped CSR)
//   [604816  .. +200000)   rowend int[NN]
//   [805632  .. +256)      tailc int[64] (zeroed by memset; bucket fill counts)
//   [806400  .. +65536)    stats1p f32[64][256]
//   [871936  .. +65536)    stats2p f32[64][256]
//   [1048576 .. +3.7MB)    csr_src int[49*CAP]
//   [4718592 .. +12.8MB)   hbuf  bf16[NN*DD] packed-slot layout (dinv-scaled)
//   [17518592.. +32768)    wp1 bf16[128*128] swizzled
//   [17551360.. +32768)    wp2 bf16[128*128] swizzled
//   [30056448.. +12.8MB)   aggbuf bf16[NN*DD] row-major
//   [42856448.. +3.7MB)    binned uint[49*CAP] packed

typedef __hip_bfloat16 bf16;
typedef __attribute__((ext_vector_type(8))) short short8;   // 8 bf16 = 4 VGPR
typedef __attribute__((ext_vector_type(4))) float f32x4;    // MFMA accumulator

#define NN 50000
#define NE 800000
#define DD 128
#define BN_EPS 1e-5f
#define BIN_CHUNK 3125   // NE / 256 exactly
#define CAP 18432        // per-bucket slot capacity (72*256; mu+16sigma)
#define NBKT 49          // ceil(50000 / 1024)

__device__ __forceinline__ float b2f(bf16 v) { return __bfloat162float(v); }
__device__ __forceinline__ float ldf(const void* p, size_t idx, int isbf) {
  return isbf ? b2f(((const bf16*)p)[idx]) : ((const float*)p)[idx];
}
__device__ __forceinline__ int lde(const void* ei, size_t idx, int is64) {
  return is64 ? (int)((const long long*)ei)[idx] : ((const int*)ei)[idx];
}
__device__ __forceinline__ unsigned int f2bs(float v) {
  bf16 b = __float2bfloat16(v);
  return (unsigned int)*reinterpret_cast<unsigned short*>(&b);
}
__device__ __forceinline__ float bslo(unsigned int u) { return __uint_as_float(u << 16); }
__device__ __forceinline__ float bshi(unsigned int u) { return __uint_as_float(u & 0xFFFF0000u); }
__device__ __forceinline__ float s2f(short v) {
  return __uint_as_float(((unsigned int)(unsigned short)v) << 16);
}

// 256 blocks x 256. Per-block dtype self-probe; block 0 publishes flags;
// blocks 0..63 swizzle W1, 64..127 swizzle W2; all bin their edge chunk into
// packed binned[] at zero-based bucket counters (tailc pre-zeroed).
__global__ __launch_bounds__(256) void k_bin(const int* ei_i, const unsigned short* x16,
                                             const void* W1, const void* W2,
                                             unsigned short* wp1, unsigned short* wp2,
                                             int* flags, int* tailc, unsigned int* binned) {
  __shared__ int cnt[64], cur[64], gb[64], sflags[2];
  __shared__ unsigned int ebuf[BIN_CHUNK];  // 12.5 KB
  const int tid = threadIdx.x;
  const int bid = blockIdx.x;
  if (tid < 64) {
    unsigned long long m1 = __ballot(ei_i[2 * tid + 1] != 0);
    int ex = (x16[2 * tid] >> 7) & 0xFF;
    unsigned long long m2 = __ballot(ex >= 90 && ex <= 140);
    if (tid == 0) {
      sflags[0] = (m1 == 0ull) ? 1 : 0;
      sflags[1] = (__popcll(m2) >= 48) ? 1 : 0;
    }
    cnt[tid] = 0;
    cur[tid] = 0;
  }
  __syncthreads();
  const int is64 = sflags[0], isbf = sflags[1];
  if (bid == 0 && tid == 0) { flags[0] = is64; flags[1] = isbf; }
  if (bid < 128) {  // W swizzle side-job
    const void* W = bid < 64 ? W1 : W2;
    unsigned short* wp = bid < 64 ? wp1 : wp2;
    int idx = (bid & 63) * 256 + tid;
    int k = idx >> 7, n = idx & 127;
    wp[(k >> 3) * 1024 + n * 8 + (k & 7)] = (unsigned short)f2bs(ldf(W, idx, isbf));
  }
  const void* ei = (const void*)ei_i;
  const int e0 = bid * BIN_CHUNK;
  for (int t = tid; t < BIN_CHUNK; t += 256) {
    int s = lde(ei, (size_t)(e0 + t), is64);
    int d = lde(ei, (size_t)NE + e0 + t, is64);
    ebuf[t] = ((unsigned)s << 16) | ((unsigned)(d >> 10) << 10) | (unsigned)(d & 1023);
    atomicAdd(&cnt[d >> 10], 1);
  }
  __syncthreads();
  if (tid < 64 && cnt[tid] > 0) gb[tid] = tid * CAP + atomicAdd(&tailc[tid], cnt[tid]);
  __syncthreads();
  for (int t = tid; t < BIN_CHUNK; t += 256) {
    unsigned int u = ebuf[t];
    int b = (int)((u >> 10) & 63);
    int r = atomicAdd(&cur[b], 1);
    binned[gb[b] + r] = u;
  }
}

// Per-bucket: degree hist (LDS) -> dinv/rowptr/rowend, then exact CSR fill
// with LDS cursors. 49 blocks x 1024. packed u: s=u>>16, dlow=u&1023.
__global__ __launch_bounds__(1024) void k_degfill(const unsigned int* binned, const int* tailc,
                                                  float* dinv, int* rowptr, int* rowend,
                                                  int* csr_src) {
  __shared__ int hist[1024];
  const int b = blockIdx.x;
  const int t = threadIdx.x;
  hist[t] = 0;
  __syncthreads();
  const int eb = b * CAP, ee = eb + tailc[b];
  for (int e = eb + t; e < ee; e += 1024) atomicAdd(&hist[binned[e] & 1023], 1);
  __syncthreads();
  int h = hist[t];
  __syncthreads();
  for (int off = 1; off < 1024; off <<= 1) {  // inclusive scan
    int u = (t >= off) ? hist[t - off] : 0;
    __syncthreads();
    hist[t] += u;
    __syncthreads();
  }
  int start = eb + hist[t] - h;  // exclusive prefix, global position
  int node = b * 1024 + t;
  if (node < NN) {
    rowptr[node] = start;
    rowend[node] = start + h;
    dinv[node] = rsqrtf((float)(h + 1));  // +1 self-loop
  }
  __syncthreads();
  hist[t] = start;  // repurpose as fill cursor
  __syncthreads();
  for (int e = eb + t; e < ee; e += 1024) {
    unsigned int u = binned[e];
    int pos = atomicAdd(&hist[u & 1023], 1);
    csr_src[pos] = (int)(u >> 16);
  }
}

// MFMA GEMM, 64 rows/block (782 blocks). out = dinv-prescaled bf16 in
// packed-slot layout: row r, u32 slot s holds bf16 pair (col s, col s+64).
// W pre-swizzled (wp), raw LDS copy. XMODE 0: layer-1 input (probe f32/bf16).
// XMODE 2: aggbuf bf16 + fused BN1 (stats from 64-copy partials statsp).
// Blocks 0..63 zero zstats (consumed by the NEXT kernel's atomics --
// stream-ordered, safe).
template <int XMODE>
__global__ __launch_bounds__(256) void k_gemm(const void* in_, const unsigned short* wp,
                                              const int* flags, const float* dinv,
                                              const float* statsp, const void* g,
                                              const void* be, const void* al,
                                              float* zstats, unsigned int* out) {
  __shared__ alignas(16) short sW[16 * 128 * 8];  // 32 KB
  __shared__ float sSc[DD], sSh[DD], sAl;
  const int isbf = flags[1];
  const int tid = threadIdx.x;

  if (blockIdx.x < 64) zstats[blockIdx.x * 256 + tid] = 0.f;
  {
    const short8* src = (const short8*)wp;
    short8* dst = (short8*)sW;
#pragma unroll
    for (int i = 0; i < 8; i++) dst[tid + i * 256] = src[tid + i * 256];
  }
  if (XMODE == 2) {
    if (tid < DD) {
      float s = 0.f, q = 0.f;
#pragma unroll 8
      for (int k = 0; k < 64; k++) {
        s += statsp[k * 256 + tid];
        q += statsp[k * 256 + 128 + tid];
      }
      const float inv_n = 1.0f / NN;
      float mu = s * inv_n;
      float var = q * inv_n - mu * mu;
      float sc = rsqrtf(var + BN_EPS) * ldf(g, tid, isbf);
      sSc[tid] = sc;
      sSh[tid] = ldf(be, tid, isbf) - mu * sc;
    }
    if (tid == 0) sAl = ldf(al, 0, isbf);
  }
  __syncthreads();

  const int wave = tid >> 6;
  const int lane = tid & 63;
  const int quad = lane >> 4;
  const int m16 = lane & 15;
  const int r0 = blockIdx.x * 64 + wave * 16;

  f32x4 acc[8];
#pragma unroll
  for (int n = 0; n < 8; n++) acc[n] = (f32x4){0.f, 0.f, 0.f, 0.f};

#pragma unroll
  for (int q = 0; q < 4; q++) {
    const int kq = q * 32 + quad * 8;
    short8 af;
    {
      int row = r0 + m16;
      row = row < NN ? row : NN - 1;  // clamp; garbage rows never stored
      if (XMODE == 2) {
        short8 raw = *(const short8*)((const short*)in_ + (size_t)row * DD + kq);
        short8 f;
#pragma unroll
        for (int jj = 0; jj < 8; jj++) {
          float y = s2f(raw[jj]);
          y = y * sSc[kq + jj] + sSh[kq + jj];
          y = y > 0.f ? y : sAl * y;
          f[jj] = (short)f2bs(y);
        }
        af = f;
      } else if (isbf) {
        af = *(const short8*)((const short*)in_ + (size_t)row * DD + kq);
      } else {
        const float* ap = (const float*)in_ + (size_t)row * DD + kq;
        const float4 u0 = *(const float4*)ap;
        const float4 u1 = *(const float4*)(ap + 4);
        float v[8] = {u0.x, u0.y, u0.z, u0.w, u1.x, u1.y, u1.z, u1.w};
        short8 f;
#pragma unroll
        for (int jj = 0; jj < 8; jj++) f[jj] = (short)f2bs(v[jj]);
        af = f;
      }
    }
    const int c = q * 4 + quad;
    const short* bp = sW + c * 1024 + m16 * 8;
#pragma unroll
    for (int n = 0; n < 8; n++) {
      const short8 bfrag = *(const short8*)(bp + n * 128);
      acc[n] = __builtin_amdgcn_mfma_f32_16x16x32_bf16(af, bfrag, acc[n], 0, 0, 0);
    }
  }

#pragma unroll
  for (int r = 0; r < 4; r++) {
    int row = r0 + quad * 4 + r;
    if (row < NN) {
      float di = dinv[row];
      unsigned int* orow = out + (size_t)row * 64;
#pragma unroll
      for (int n = 0; n < 4; n++) {
        unsigned int p = (f2bs(di * acc[n + 4][r]) << 16) | f2bs(di * acc[n][r]);
        orow[n * 16 + m16] = p;
      }
    }
  }
}

// One wave per node (12500 blocks = 50000 waves exactly). Row range
// [rowptr[w], rowend[w]) in the gapped CSR, forced into SGPRs via
// readfirstlane: index loads take the scalar pipe (s_load), loop control is
// SALU, each gather costs 1 dest VGPR. 16-deep gather window, then 4, then 1.
__global__ __launch_bounds__(256) void k_agg(const unsigned int* hs, const float* dinv,
                                             const int* rowptr, const int* rowend,
                                             const int* csr_src, const void* bias,
                                             const int* flags, unsigned short* out,
                                             float* statsp) {
  const int tid = threadIdx.x;
  const int w = (blockIdx.x * 256 + tid) >> 6;   // never >= NN (12500*4 == NN)
  const int lane = tid & 63;
  const float dd_ = dinv[w];
  unsigned int hv = hs[(size_t)w * 64 + lane];
  float ax = bslo(hv), ay = bshi(hv);
  int e = __builtin_amdgcn_readfirstlane(rowptr[w]);
  const int e1 = __builtin_amdgcn_readfirstlane(rowend[w]);

  for (; e + 16 <= e1; e += 16) {
    int s[16];
#pragma unroll
    for (int k = 0; k < 16; k++) s[k] = csr_src[e + k];
    unsigned int v[16];
#pragma unroll
    for (int k = 0; k < 16; k++) v[k] = hs[(size_t)s[k] * 64 + lane];
#pragma unroll
    for (int k = 0; k < 16; k++) { ax += bslo(v[k]); ay += bshi(v[k]); }
  }
  for (; e + 4 <= e1; e += 4) {
    int s[4];
#pragma unroll
    for (int k = 0; k < 4; k++) s[k] = csr_src[e + k];
    unsigned int v[4];
#pragma unroll
    for (int k = 0; k < 4; k++) v[k] = hs[(size_t)s[k] * 64 + lane];
#pragma unroll
    for (int k = 0; k < 4; k++) { ax += bslo(v[k]); ay += bshi(v[k]); }
  }
  for (; e < e1; e++) {
    unsigned int v0 = hs[(size_t)csr_src[e] * 64 + lane];
    ax += bslo(v0);
    ay += bshi(v0);
  }

  int isbf = flags[1];
  float o1 = dd_ * ax + ldf(bias, lane, isbf);
  float o2 = dd_ * ay + ldf(bias, lane + 64, isbf);
  unsigned short* orow = out + (size_t)w * DD;
  orow[lane] = (unsigned short)f2bs(o1);
  orow[lane + 64] = (unsigned short)f2bs(o2);

  __shared__ float rs1[256], rq1[256], rs2[256], rq2[256];
  rs1[tid] = o1; rq1[tid] = o1 * o1;
  rs2[tid] = o2; rq2[tid] = o2 * o2;
  __syncthreads();
  float* p = statsp + (blockIdx.x & 63) * 256;
  if (tid < 64) {  // col tid
    float s = rs1[tid] + rs1[tid + 64] + rs1[tid + 128] + rs1[tid + 192];
    float q = rq1[tid] + rq1[tid + 64] + rq1[tid + 128] + rq1[tid + 192];
    atomicAdd(&p[tid], s);
    atomicAdd(&p[128 + tid], q);
  } else if (tid < 128) {  // col tid (= 64 + lane)
    int l = tid - 64;
    float s = rs2[l] + rs2[l + 64] + rs2[l + 128] + rs2[l + 192];
    float q = rq2[l] + rq2[l + 64] + rq2[l + 128] + rq2[l + 192];
    atomicAdd(&p[tid], s);
    atomicAdd(&p[128 + tid], q);
  }
}

// Final BN+PReLU: 1024 grid-stride blocks. Prologue sums the 64 stat copies
// into LDS sc/sh (one rsqrt per column per block, not per element).
__global__ __launch_bounds__(256) void k_bn_apply(const unsigned int* x32, const float* statsp,
                                                  const void* g, const void* be, const void* al,
                                                  const int* flags, void* out) {
  __shared__ float sSc[DD], sSh[DD], sAl;
  const int tid = threadIdx.x;
  const int isbf = flags[1];
  if (tid < DD) {
    float s = 0.f, q = 0.f;
#pragma unroll 8
    for (int k = 0; k < 64; k++) {
      s += statsp[k * 256 + tid];
      q += statsp[k * 256 + 128 + tid];
    }
    const float inv_n = 1.0f / NN;
    float mu = s * inv_n;
    float var = q * inv_n - mu * mu;
    float sc = rsqrtf(var + BN_EPS) * ldf(g, tid, isbf);
    sSc[tid] = sc;
    sSh[tid] = ldf(be, tid, isbf) - mu * sc;
  }
  if (tid == 0) sAl = ldf(al, 0, isbf);
  __syncthreads();
  const float alpha = sAl;
  for (int i4 = blockIdx.x * 256 + tid; i4 < NN * 32; i4 += gridDim.x * 256) {
    int jq = (i4 & 31) * 4;
    const uint2 xv = ((const uint2*)x32)[i4];
    float xa[4] = {bslo(xv.x), bshi(xv.x), bslo(xv.y), bshi(xv.y)};
    float y[4];
#pragma unroll
    for (int u = 0; u < 4; u++) {
      int j = jq + u;
      float v = xa[u] * sSc[j] + sSh[j];
      y[u] = v > 0.f ? v : alpha * v;
    }
    if (isbf) {
      uint2 o;
      o.x = (f2bs(y[1]) << 16) | f2bs(y[0]);
      o.y = (f2bs(y[3]) << 16) | f2bs(y[2]);
      ((uint2*)out)[i4] = o;
    } else {
      float4 o = {y[0], y[1], y[2], y[3]};
      ((float4*)out)[i4] = o;
    }
  }
}

extern "C" void kernel_launch(void* const* d_in, const int* in_sizes, int n_in,
                              void* d_out, int out_size, void* d_ws, size_t ws_size,
                              hipStream_t stream) {
  const void* x = d_in[0];
  const int* ei = (const int*)d_in[1];
  const void* W1 = d_in[2];
  const void* b1 = d_in[3];
  const void* g1 = d_in[4];
  const void* be1 = d_in[5];
  const void* a1 = d_in[6];
  const void* W2 = d_in[7];
  const void* b2 = d_in[8];
  const void* g2 = d_in[9];
  const void* be2 = d_in[10];
  const void* a2 = d_in[11];

  char* w = (char*)d_ws;
  float* dinv = (float*)w;                              // 200000
  int* flags = (int*)(w + 200704);                      // 8
  int* rowptr = (int*)(w + 404800);                     // 200000
  int* rowend = (int*)(w + 604816);                     // 200000
  int* tailc = (int*)(w + 805632);                      // 256
  float* stats1p = (float*)(w + 806400);                // 65536
  float* stats2p = (float*)(w + 871936);                // 65536
  int* csr_src = (int*)(w + 1048576);                   // 3612672
  unsigned int* hbuf = (unsigned int*)(w + 4718592);    // 12800000
  unsigned short* wp1 = (unsigned short*)(w + 17518592);   // 32768
  unsigned short* wp2 = (unsigned short*)(w + 17551360);   // 32768
  unsigned short* aggbuf = (unsigned short*)(w + 30056448);  // 12800000
  unsigned int* binned = (unsigned int*)(w + 42856448);  // 3612672

  const int NB_G = (NN + 63) / 64;     // 782
  const int NB_W = NN * 64 / 256;      // 12500

  hipMemsetAsync(tailc, 0, 256, stream);
  k_bin<<<dim3(256), dim3(256), 0, stream>>>(ei, (const unsigned short*)x, W1, W2,
                                             wp1, wp2, flags, tailc, binned);
  k_degfill<<<dim3(NBKT), dim3(1024), 0, stream>>>(binned, tailc, dinv, rowptr, rowend,
                                                   csr_src);

  // ---- layer 1 ----
  k_gemm<0><<<dim3(NB_G), dim3(256), 0, stream>>>(x, wp1, flags, dinv,
                                                  nullptr, nullptr, nullptr, nullptr,
                                                  stats1p, hbuf);
  k_agg<<<dim3(NB_W), dim3(256), 0, stream>>>(hbuf, dinv, rowptr, rowend, csr_src,
                                              b1, flags, aggbuf, stats1p);

  // ---- layer 2 (BN1+PReLU fused into GEMM A-path via stats1p) ----
  k_gemm<2><<<dim3(NB_G), dim3(256), 0, stream>>>(aggbuf, wp2, flags, dinv,
                                                  stats1p, g1, be1, a1, stats2p, hbuf);
  k_agg<<<dim3(NB_W), dim3(256), 0, stream>>>(hbuf, dinv, rowptr, rowend, csr_src,
                                              b2, flags, aggbuf, stats2p);
  k_bn_apply<<<dim3(1024), dim3(256), 0, stream>>>((const unsigned int*)aggbuf, stats2p,
                                                   g2, be2, a2, flags, d_out);
}

// Round 6
// 219.422 us; speedup vs baseline: 1.5015x; 1.0215x over previous
//
#include <hip/hip_runtime.h>
#include <hip/hip_bf16.h>

// 2-layer GCN encoder: (GCNConv -> BatchNorm1d(train) -> PReLU) x 2
// N=50000, E=800000, D=128. Inputs f32 (probed), edge_index int64 (probed),
// output f32. Internal: GEMM/agg buffers bf16, math f32.
//
// R19: k_agg tail fix. Mean degree = 16 exactly (Poisson, sigma~4); R17's
// 4-deep + 1-deep remainder loops cost up to 6 serial LLC round-trips per
// node, and nodes with degree<16 (half of them) never reached the 16-deep
// window. Replace both tails with ONE predicated 16-deep batch: clamp index
// e+(k<r?k:0) keeps loads unconditional (dup addrs are cache hits), masked
// branch-free accumulate. Max gather round-trips per node = ceil(deg/16).
// k_gemm stays R18 (64 rows/block), bin/degfill/bn unchanged.
//
// ws layout (bytes):
//   [0       .. +200000)   dinv f32[NN]
//   [200704  .. +8)        flags: [0]=int64?, [1]=bf16-floats?
//   [404800  .. +200000)   rowptr int[NN] (row starts, gapped CSR)
//   [604816  .. +200000)   rowend int[NN]
//   [805632  .. +256)      tailc int[64] (zeroed by memset; bucket fill counts)
//   [806400  .. +65536)    stats1p f32[64][256]
//   [871936  .. +65536)    stats2p f32[64][256]
//   [1048576 .. +3.7MB)    csr_src int[49*CAP]
//   [4718592 .. +12.8MB)   hbuf  bf16[NN*DD] packed-slot layout (dinv-scaled)
//   [17518592.. +32768)    wp1 bf16[128*128] swizzled
//   [17551360.. +32768)    wp2 bf16[128*128] swizzled
//   [30056448.. +12.8MB)   aggbuf bf16[NN*DD] row-major
//   [42856448.. +3.7MB)    binned uint[49*CAP] packed

typedef __hip_bfloat16 bf16;
typedef __attribute__((ext_vector_type(8))) short short8;   // 8 bf16 = 4 VGPR
typedef __attribute__((ext_vector_type(4))) float f32x4;    // MFMA accumulator

#define NN 50000
#define NE 800000
#define DD 128
#define BN_EPS 1e-5f
#define BIN_CHUNK 3125   // NE / 256 exactly
#define CAP 18432        // per-bucket slot capacity (72*256; mu+16sigma)
#define NBKT 49          // ceil(50000 / 1024)

__device__ __forceinline__ float b2f(bf16 v) { return __bfloat162float(v); }
__device__ __forceinline__ float ldf(const void* p, size_t idx, int isbf) {
  return isbf ? b2f(((const bf16*)p)[idx]) : ((const float*)p)[idx];
}
__device__ __forceinline__ int lde(const void* ei, size_t idx, int is64) {
  return is64 ? (int)((const long long*)ei)[idx] : ((const int*)ei)[idx];
}
__device__ __forceinline__ unsigned int f2bs(float v) {
  bf16 b = __float2bfloat16(v);
  return (unsigned int)*reinterpret_cast<unsigned short*>(&b);
}
__device__ __forceinline__ float bslo(unsigned int u) { return __uint_as_float(u << 16); }
__device__ __forceinline__ float bshi(unsigned int u) { return __uint_as_float(u & 0xFFFF0000u); }
__device__ __forceinline__ float s2f(short v) {
  return __uint_as_float(((unsigned int)(unsigned short)v) << 16);
}

// 256 blocks x 256. Per-block dtype self-probe; block 0 publishes flags;
// blocks 0..63 swizzle W1, 64..127 swizzle W2; all bin their edge chunk into
// packed binned[] at zero-based bucket counters (tailc pre-zeroed).
__global__ __launch_bounds__(256) void k_bin(const int* ei_i, const unsigned short* x16,
                                             const void* W1, const void* W2,
                                             unsigned short* wp1, unsigned short* wp2,
                                             int* flags, int* tailc, unsigned int* binned) {
  __shared__ int cnt[64], cur[64], gb[64], sflags[2];
  __shared__ unsigned int ebuf[BIN_CHUNK];  // 12.5 KB
  const int tid = threadIdx.x;
  const int bid = blockIdx.x;
  if (tid < 64) {
    unsigned long long m1 = __ballot(ei_i[2 * tid + 1] != 0);
    int ex = (x16[2 * tid] >> 7) & 0xFF;
    unsigned long long m2 = __ballot(ex >= 90 && ex <= 140);
    if (tid == 0) {
      sflags[0] = (m1 == 0ull) ? 1 : 0;
      sflags[1] = (__popcll(m2) >= 48) ? 1 : 0;
    }
    cnt[tid] = 0;
    cur[tid] = 0;
  }
  __syncthreads();
  const int is64 = sflags[0], isbf = sflags[1];
  if (bid == 0 && tid == 0) { flags[0] = is64; flags[1] = isbf; }
  if (bid < 128) {  // W swizzle side-job
    const void* W = bid < 64 ? W1 : W2;
    unsigned short* wp = bid < 64 ? wp1 : wp2;
    int idx = (bid & 63) * 256 + tid;
    int k = idx >> 7, n = idx & 127;
    wp[(k >> 3) * 1024 + n * 8 + (k & 7)] = (unsigned short)f2bs(ldf(W, idx, isbf));
  }
  const void* ei = (const void*)ei_i;
  const int e0 = bid * BIN_CHUNK;
  for (int t = tid; t < BIN_CHUNK; t += 256) {
    int s = lde(ei, (size_t)(e0 + t), is64);
    int d = lde(ei, (size_t)NE + e0 + t, is64);
    ebuf[t] = ((unsigned)s << 16) | ((unsigned)(d >> 10) << 10) | (unsigned)(d & 1023);
    atomicAdd(&cnt[d >> 10], 1);
  }
  __syncthreads();
  if (tid < 64 && cnt[tid] > 0) gb[tid] = tid * CAP + atomicAdd(&tailc[tid], cnt[tid]);
  __syncthreads();
  for (int t = tid; t < BIN_CHUNK; t += 256) {
    unsigned int u = ebuf[t];
    int b = (int)((u >> 10) & 63);
    int r = atomicAdd(&cur[b], 1);
    binned[gb[b] + r] = u;
  }
}

// Per-bucket: degree hist (LDS) -> dinv/rowptr/rowend, then exact CSR fill
// with LDS cursors. 49 blocks x 1024. packed u: s=u>>16, dlow=u&1023.
__global__ __launch_bounds__(1024) void k_degfill(const unsigned int* binned, const int* tailc,
                                                  float* dinv, int* rowptr, int* rowend,
                                                  int* csr_src) {
  __shared__ int hist[1024];
  const int b = blockIdx.x;
  const int t = threadIdx.x;
  hist[t] = 0;
  __syncthreads();
  const int eb = b * CAP, ee = eb + tailc[b];
  for (int e = eb + t; e < ee; e += 1024) atomicAdd(&hist[binned[e] & 1023], 1);
  __syncthreads();
  int h = hist[t];
  __syncthreads();
  for (int off = 1; off < 1024; off <<= 1) {  // inclusive scan
    int u = (t >= off) ? hist[t - off] : 0;
    __syncthreads();
    hist[t] += u;
    __syncthreads();
  }
  int start = eb + hist[t] - h;  // exclusive prefix, global position
  int node = b * 1024 + t;
  if (node < NN) {
    rowptr[node] = start;
    rowend[node] = start + h;
    dinv[node] = rsqrtf((float)(h + 1));  // +1 self-loop
  }
  __syncthreads();
  hist[t] = start;  // repurpose as fill cursor
  __syncthreads();
  for (int e = eb + t; e < ee; e += 1024) {
    unsigned int u = binned[e];
    int pos = atomicAdd(&hist[u & 1023], 1);
    csr_src[pos] = (int)(u >> 16);
  }
}

// MFMA GEMM, 64 rows/block (782 blocks). out = dinv-prescaled bf16 in
// packed-slot layout: row r, u32 slot s holds bf16 pair (col s, col s+64).
// W pre-swizzled (wp), raw LDS copy. XMODE 0: layer-1 input (probe f32/bf16).
// XMODE 2: aggbuf bf16 + fused BN1 (stats from 64-copy partials statsp).
// Blocks 0..63 zero zstats (consumed by the NEXT kernel's atomics --
// stream-ordered, safe).
template <int XMODE>
__global__ __launch_bounds__(256) void k_gemm(const void* in_, const unsigned short* wp,
                                              const int* flags, const float* dinv,
                                              const float* statsp, const void* g,
                                              const void* be, const void* al,
                                              float* zstats, unsigned int* out) {
  __shared__ alignas(16) short sW[16 * 128 * 8];  // 32 KB
  __shared__ float sSc[DD], sSh[DD], sAl;
  const int isbf = flags[1];
  const int tid = threadIdx.x;

  if (blockIdx.x < 64) zstats[blockIdx.x * 256 + tid] = 0.f;
  {
    const short8* src = (const short8*)wp;
    short8* dst = (short8*)sW;
#pragma unroll
    for (int i = 0; i < 8; i++) dst[tid + i * 256] = src[tid + i * 256];
  }
  if (XMODE == 2) {
    if (tid < DD) {
      float s = 0.f, q = 0.f;
#pragma unroll 8
      for (int k = 0; k < 64; k++) {
        s += statsp[k * 256 + tid];
        q += statsp[k * 256 + 128 + tid];
      }
      const float inv_n = 1.0f / NN;
      float mu = s * inv_n;
      float var = q * inv_n - mu * mu;
      float sc = rsqrtf(var + BN_EPS) * ldf(g, tid, isbf);
      sSc[tid] = sc;
      sSh[tid] = ldf(be, tid, isbf) - mu * sc;
    }
    if (tid == 0) sAl = ldf(al, 0, isbf);
  }
  __syncthreads();

  const int wave = tid >> 6;
  const int lane = tid & 63;
  const int quad = lane >> 4;
  const int m16 = lane & 15;
  const int r0 = blockIdx.x * 64 + wave * 16;

  f32x4 acc[8];
#pragma unroll
  for (int n = 0; n < 8; n++) acc[n] = (f32x4){0.f, 0.f, 0.f, 0.f};

#pragma unroll
  for (int q = 0; q < 4; q++) {
    const int kq = q * 32 + quad * 8;
    short8 af;
    {
      int row = r0 + m16;
      row = row < NN ? row : NN - 1;  // clamp; garbage rows never stored
      if (XMODE == 2) {
        short8 raw = *(const short8*)((const short*)in_ + (size_t)row * DD + kq);
        short8 f;
#pragma unroll
        for (int jj = 0; jj < 8; jj++) {
          float y = s2f(raw[jj]);
          y = y * sSc[kq + jj] + sSh[kq + jj];
          y = y > 0.f ? y : sAl * y;
          f[jj] = (short)f2bs(y);
        }
        af = f;
      } else if (isbf) {
        af = *(const short8*)((const short*)in_ + (size_t)row * DD + kq);
      } else {
        const float* ap = (const float*)in_ + (size_t)row * DD + kq;
        const float4 u0 = *(const float4*)ap;
        const float4 u1 = *(const float4*)(ap + 4);
        float v[8] = {u0.x, u0.y, u0.z, u0.w, u1.x, u1.y, u1.z, u1.w};
        short8 f;
#pragma unroll
        for (int jj = 0; jj < 8; jj++) f[jj] = (short)f2bs(v[jj]);
        af = f;
      }
    }
    const int c = q * 4 + quad;
    const short* bp = sW + c * 1024 + m16 * 8;
#pragma unroll
    for (int n = 0; n < 8; n++) {
      const short8 bfrag = *(const short8*)(bp + n * 128);
      acc[n] = __builtin_amdgcn_mfma_f32_16x16x32_bf16(af, bfrag, acc[n], 0, 0, 0);
    }
  }

#pragma unroll
  for (int r = 0; r < 4; r++) {
    int row = r0 + quad * 4 + r;
    if (row < NN) {
      float di = dinv[row];
      unsigned int* orow = out + (size_t)row * 64;
#pragma unroll
      for (int n = 0; n < 4; n++) {
        unsigned int p = (f2bs(di * acc[n + 4][r]) << 16) | f2bs(di * acc[n][r]);
        orow[n * 16 + m16] = p;
      }
    }
  }
}

// One wave per node (12500 blocks = 50000 waves exactly). Row range
// [rowptr[w], rowend[w]) in the gapped CSR via readfirstlane -> scalar pipe.
// Main loop: 16-deep gather window. Remainder r in [1,16): ONE predicated
// 16-deep batch (index clamp e+(k<r?k:0); dup addrs = cache hits; masked
// branch-free accumulate) instead of serial 4-deep/1-deep tails.
__global__ __launch_bounds__(256) void k_agg(const unsigned int* hs, const float* dinv,
                                             const int* rowptr, const int* rowend,
                                             const int* csr_src, const void* bias,
                                             const int* flags, unsigned short* out,
                                             float* statsp) {
  const int tid = threadIdx.x;
  const int w = (blockIdx.x * 256 + tid) >> 6;   // never >= NN (12500*4 == NN)
  const int lane = tid & 63;
  const float dd_ = dinv[w];
  unsigned int hv = hs[(size_t)w * 64 + lane];
  float ax = bslo(hv), ay = bshi(hv);
  int e = __builtin_amdgcn_readfirstlane(rowptr[w]);
  const int e1 = __builtin_amdgcn_readfirstlane(rowend[w]);

  for (; e + 16 <= e1; e += 16) {
    int s[16];
#pragma unroll
    for (int k = 0; k < 16; k++) s[k] = csr_src[e + k];
    unsigned int v[16];
#pragma unroll
    for (int k = 0; k < 16; k++) v[k] = hs[(size_t)s[k] * 64 + lane];
#pragma unroll
    for (int k = 0; k < 16; k++) { ax += bslo(v[k]); ay += bshi(v[k]); }
  }
  const int r = e1 - e;  // 0..15, wave-uniform
  if (r > 0) {
    int s[16];
#pragma unroll
    for (int k = 0; k < 16; k++) s[k] = csr_src[e + (k < r ? k : 0)];
    unsigned int v[16];
#pragma unroll
    for (int k = 0; k < 16; k++) v[k] = hs[(size_t)s[k] * 64 + lane];
#pragma unroll
    for (int k = 0; k < 16; k++) {
      const float m = (k < r) ? 1.f : 0.f;
      ax += m * bslo(v[k]);
      ay += m * bshi(v[k]);
    }
  }

  int isbf = flags[1];
  float o1 = dd_ * ax + ldf(bias, lane, isbf);
  float o2 = dd_ * ay + ldf(bias, lane + 64, isbf);
  unsigned short* orow = out + (size_t)w * DD;
  orow[lane] = (unsigned short)f2bs(o1);
  orow[lane + 64] = (unsigned short)f2bs(o2);

  __shared__ float rs1[256], rq1[256], rs2[256], rq2[256];
  rs1[tid] = o1; rq1[tid] = o1 * o1;
  rs2[tid] = o2; rq2[tid] = o2 * o2;
  __syncthreads();
  float* p = statsp + (blockIdx.x & 63) * 256;
  if (tid < 64) {  // col tid
    float s = rs1[tid] + rs1[tid + 64] + rs1[tid + 128] + rs1[tid + 192];
    float q = rq1[tid] + rq1[tid + 64] + rq1[tid + 128] + rq1[tid + 192];
    atomicAdd(&p[tid], s);
    atomicAdd(&p[128 + tid], q);
  } else if (tid < 128) {  // col tid (= 64 + lane)
    int l = tid - 64;
    float s = rs2[l] + rs2[l + 64] + rs2[l + 128] + rs2[l + 192];
    float q = rq2[l] + rq2[l + 64] + rq2[l + 128] + rq2[l + 192];
    atomicAdd(&p[tid], s);
    atomicAdd(&p[128 + tid], q);
  }
}

// Final BN+PReLU: 1024 grid-stride blocks. Prologue sums the 64 stat copies
// into LDS sc/sh (one rsqrt per column per block, not per element).
__global__ __launch_bounds__(256) void k_bn_apply(const unsigned int* x32, const float* statsp,
                                                  const void* g, const void* be, const void* al,
                                                  const int* flags, void* out) {
  __shared__ float sSc[DD], sSh[DD], sAl;
  const int tid = threadIdx.x;
  const int isbf = flags[1];
  if (tid < DD) {
    float s = 0.f, q = 0.f;
#pragma unroll 8
    for (int k = 0; k < 64; k++) {
      s += statsp[k * 256 + tid];
      q += statsp[k * 256 + 128 + tid];
    }
    const float inv_n = 1.0f / NN;
    float mu = s * inv_n;
    float var = q * inv_n - mu * mu;
    float sc = rsqrtf(var + BN_EPS) * ldf(g, tid, isbf);
    sSc[tid] = sc;
    sSh[tid] = ldf(be, tid, isbf) - mu * sc;
  }
  if (tid == 0) sAl = ldf(al, 0, isbf);
  __syncthreads();
  const float alpha = sAl;
  for (int i4 = blockIdx.x * 256 + tid; i4 < NN * 32; i4 += gridDim.x * 256) {
    int jq = (i4 & 31) * 4;
    const uint2 xv = ((const uint2*)x32)[i4];
    float xa[4] = {bslo(xv.x), bshi(xv.x), bslo(xv.y), bshi(xv.y)};
    float y[4];
#pragma unroll
    for (int u = 0; u < 4; u++) {
      int j = jq + u;
      float v = xa[u] * sSc[j] + sSh[j];
      y[u] = v > 0.f ? v : alpha * v;
    }
    if (isbf) {
      uint2 o;
      o.x = (f2bs(y[1]) << 16) | f2bs(y[0]);
      o.y = (f2bs(y[3]) << 16) | f2bs(y[2]);
      ((uint2*)out)[i4] = o;
    } else {
      float4 o = {y[0], y[1], y[2], y[3]};
      ((float4*)out)[i4] = o;
    }
  }
}

extern "C" void kernel_launch(void* const* d_in, const int* in_sizes, int n_in,
                              void* d_out, int out_size, void* d_ws, size_t ws_size,
                              hipStream_t stream) {
  const void* x = d_in[0];
  const int* ei = (const int*)d_in[1];
  const void* W1 = d_in[2];
  const void* b1 = d_in[3];
  const void* g1 = d_in[4];
  const void* be1 = d_in[5];
  const void* a1 = d_in[6];
  const void* W2 = d_in[7];
  const void* b2 = d_in[8];
  const void* g2 = d_in[9];
  const void* be2 = d_in[10];
  const void* a2 = d_in[11];

  char* w = (char*)d_ws;
  float* dinv = (float*)w;                              // 200000
  int* flags = (int*)(w + 200704);                      // 8
  int* rowptr = (int*)(w + 404800);                     // 200000
  int* rowend = (int*)(w + 604816);                     // 200000
  int* tailc = (int*)(w + 805632);                      // 256
  float* stats1p = (float*)(w + 806400);                // 65536
  float* stats2p = (float*)(w + 871936);                // 65536
  int* csr_src = (int*)(w + 1048576);                   // 3612672
  unsigned int* hbuf = (unsigned int*)(w + 4718592);    // 12800000
  unsigned short* wp1 = (unsigned short*)(w + 17518592);   // 32768
  unsigned short* wp2 = (unsigned short*)(w + 17551360);   // 32768
  unsigned short* aggbuf = (unsigned short*)(w + 30056448);  // 12800000
  unsigned int* binned = (unsigned int*)(w + 42856448);  // 3612672

  const int NB_G = (NN + 63) / 64;     // 782
  const int NB_W = NN * 64 / 256;      // 12500

  hipMemsetAsync(tailc, 0, 256, stream);
  k_bin<<<dim3(256), dim3(256), 0, stream>>>(ei, (const unsigned short*)x, W1, W2,
                                             wp1, wp2, flags, tailc, binned);
  k_degfill<<<dim3(NBKT), dim3(1024), 0, stream>>>(binned, tailc, dinv, rowptr, rowend,
                                                   csr_src);

  // ---- layer 1 ----
  k_gemm<0><<<dim3(NB_G), dim3(256), 0, stream>>>(x, wp1, flags, dinv,
                                                  nullptr, nullptr, nullptr, nullptr,
                                                  stats1p, hbuf);
  k_agg<<<dim3(NB_W), dim3(256), 0, stream>>>(hbuf, dinv, rowptr, rowend, csr_src,
                                              b1, flags, aggbuf, stats1p);

  // ---- layer 2 (BN1+PReLU fused into GEMM A-path via stats1p) ----
  k_gemm<2><<<dim3(NB_G), dim3(256), 0, stream>>>(aggbuf, wp2, flags, dinv,
                                                  stats1p, g1, be1, a1, stats2p, hbuf);
  k_agg<<<dim3(NB_W), dim3(256), 0, stream>>>(hbuf, dinv, rowptr, rowend, csr_src,
                                              b2, flags, aggbuf, stats2p);
  k_bn_apply<<<dim3(1024), dim3(256), 0, stream>>>((const unsigned int*)aggbuf, stats2p,
                                                   g2, be2, a2, flags, d_out);
}